// Round 14
// baseline (578.892 us; speedup 1.0000x reference)
//
#include <hip/hip_runtime.h>
#include <math.h>

// Capsule routing, fused. Both GEMMs via bf16 hi/lo-split MFMA (hh+hl+lh).
// x: [256][9216] f32   W: [1152][10][16][8] f32
// out: v [256][10][16] (40960) then c_out broadcast [256][1152][10] (2949120)
// 8 launches: last-finisher fusion (ticket + device-scope fence) folds the
// split-K reduce into the GEMM dispatch and softmax into the agreement GEMM.

typedef __attribute__((ext_vector_type(8))) short short8v;
typedef __attribute__((ext_vector_type(4))) float f32x4;

__device__ __forceinline__ unsigned short f2bf(float f) {
    unsigned u = __float_as_uint(f);
    u += 0x7FFFu + ((u >> 16) & 1u);          // round-to-nearest-even
    return (unsigned short)(u >> 16);
}
__device__ __forceinline__ float bf2f(unsigned short h) {
    return __uint_as_float(((unsigned)h) << 16);
}
__device__ __forceinline__ void spin_until(unsigned* cnt, unsigned target) {
    int guard = 0;
    while (atomicAdd(cnt, 0u) < target && guard < (1 << 27)) {
        __builtin_amdgcn_s_sleep(8);
        ++guard;
    }
}

// ---------------------------------------------------------------------------
// k_prep: bid<2304: x -> bf16 hi/lo (row-major [b][k]).
//         2304..2879: const-scaled (1/1152) W' hi/lo in [n][k].
//         2880..3455: xT hi/lo [m=9216][b=256] via LDS transpose.
//         bid==0 also zeroes the 8 ticket counters.
__global__ __launch_bounds__(256) void k_prep(const float* __restrict__ x,
                                              const float* __restrict__ W,
                                              unsigned short* __restrict__ xh,
                                              unsigned short* __restrict__ xl,
                                              unsigned short* __restrict__ wph,
                                              unsigned short* __restrict__ wpl,
                                              unsigned short* __restrict__ xTh,
                                              unsigned short* __restrict__ xTl,
                                              unsigned* __restrict__ cnts)
{
    const int tid = threadIdx.x;
    if (blockIdx.x == 0 && tid < 8) cnts[tid] = 0u;
    if (blockIdx.x < 2304) {
        const int i = blockIdx.x * 256 + tid;   // float4 index, 589824 total
        const float4 v = reinterpret_cast<const float4*>(x)[i];
        const unsigned short h0 = f2bf(v.x), h1 = f2bf(v.y), h2 = f2bf(v.z), h3 = f2bf(v.w);
        const unsigned short l0 = f2bf(v.x - bf2f(h0)), l1 = f2bf(v.y - bf2f(h1)),
                             l2 = f2bf(v.z - bf2f(h2)), l3 = f2bf(v.w - bf2f(h3));
        reinterpret_cast<uint2*>(xh)[i] =
            make_uint2((unsigned)h0 | ((unsigned)h1 << 16), (unsigned)h2 | ((unsigned)h3 << 16));
        reinterpret_cast<uint2*>(xl)[i] =
            make_uint2((unsigned)l0 | ((unsigned)l1 << 16), (unsigned)l2 | ((unsigned)l3 << 16));
    } else if (blockIdx.x < 2880) {
        __shared__ float raw[2560];
        const int r0 = (blockIdx.x - 2304) * 2;
        const float sc = 1.0f / 1152.0f;
        const float4* __restrict__ W4 = reinterpret_cast<const float4*>(W) + (size_t)r0 * 320;
#pragma unroll
        for (int q = 0; q < 3; ++q) {
            const int idx = q * 256 + tid;
            if (idx < 640) *reinterpret_cast<float4*>(&raw[idx * 4]) = W4[idx];
        }
        __syncthreads();
#pragma unroll
        for (int q = 0; q < 10; ++q) {
            const int idx = q * 256 + tid;           // 0..2559
            const int n = idx >> 4, kloc = idx & 15;
            const int rl = kloc >> 3, i = kloc & 7, c = n >> 4, o = n & 15;
            const float wv = raw[rl * 1280 + c * 128 + o * 8 + i] * sc;
            const unsigned short h = f2bf(wv);
            const size_t off = (size_t)n * 9216 + r0 * 8 + kloc;
            wph[off] = h;
            wpl[off] = f2bf(wv - bf2f(h));
        }
    } else {
        // xT transpose+split: m-chunk of 16, all 256 b.
        __shared__ short Th[16][256];
        __shared__ short Tl[16][256];
        const int m0 = (blockIdx.x - 2880) * 16;
        const int b = tid;
#pragma unroll
        for (int q = 0; q < 4; ++q) {
            const float4 v = reinterpret_cast<const float4*>(x)[(size_t)b * 2304 + (m0 >> 2) + q];
            const unsigned short h0 = f2bf(v.x), h1 = f2bf(v.y), h2 = f2bf(v.z), h3 = f2bf(v.w);
            Th[q * 4 + 0][b] = (short)h0;
            Th[q * 4 + 1][b] = (short)h1;
            Th[q * 4 + 2][b] = (short)h2;
            Th[q * 4 + 3][b] = (short)h3;
            Tl[q * 4 + 0][b] = (short)f2bf(v.x - bf2f(h0));
            Tl[q * 4 + 1][b] = (short)f2bf(v.y - bf2f(h1));
            Tl[q * 4 + 2][b] = (short)f2bf(v.z - bf2f(h2));
            Tl[q * 4 + 3][b] = (short)f2bf(v.w - bf2f(h3));
        }
        __syncthreads();
        const int m = tid >> 4, seg = tid & 15;
        const size_t o = (size_t)(m0 + m) * 256 + seg * 16;
        *reinterpret_cast<uint4*>(xTh + o) = *reinterpret_cast<const uint4*>(&Th[m][seg * 16]);
        *reinterpret_cast<uint4*>(xTh + o + 8) = *reinterpret_cast<const uint4*>(&Th[m][seg * 16 + 8]);
        *reinterpret_cast<uint4*>(xTl + o) = *reinterpret_cast<const uint4*>(&Tl[m][seg * 16]);
        *reinterpret_cast<uint4*>(xTl + o + 8) = *reinterpret_cast<const uint4*>(&Tl[m][seg * 16 + 8]);
    }
}

// ---------------------------------------------------------------------------
// k_sMr: k_sM (v2 + XCD swizzle) with fused split-K reduce via last-finisher
// tickets. grid 768; work = kb(96) x mt(4) x nt(2); block 256; 30.7 KB LDS.
// All 768 blocks co-resident (3/CU) -> post-work spin is deadlock-free.
// mode 0: finishers write squashed vT hi/lo (one b each, 256 finishers).
// mode 1: finishers write squashed v into out (tickets 512..671 -> 160 e-blocks).
__global__ __launch_bounds__(256) void k_sMr(const unsigned short* __restrict__ xh,
                                             const unsigned short* __restrict__ xl,
                                             const unsigned short* __restrict__ wph,
                                             const unsigned short* __restrict__ wpl,
                                             float* __restrict__ s_part,
                                             unsigned short* __restrict__ vTh,
                                             unsigned short* __restrict__ vTl,
                                             float* __restrict__ vout,
                                             int mode,
                                             unsigned* __restrict__ cnt)
{
    __shared__ alignas(16) short Bs[2][12][80][8];   // 30720 B
    __shared__ unsigned tkt;
    const int bid  = blockIdx.x;
    const int xcd  = bid & 7;
    const int j    = bid >> 3;            // 0..95
    const int kb   = (j % 12) * 8 + xcd;  // 0..95
    const int mtnt = j / 12;              // 0..7
    const int mt = mtnt >> 1;
    const int nt = mtnt & 1;
    const int tid  = threadIdx.x;
    const int w    = tid >> 6;
    const int lane = tid & 63;
    const int l15  = lane & 15;
    const int lqw  = lane >> 4;
    const int row  = mt * 64 + w * 16 + l15;
    const int n0   = nt * 80;

    // A prefetch (6 global loads; latency hides under B staging + barrier)
    short8v ah[3], al[3];
    const size_t arow = (size_t)row * 9216 + kb * 96 + lqw * 8;
#pragma unroll
    for (int ks = 0; ks < 3; ++ks) {
        ah[ks] = *reinterpret_cast<const short8v*>(xh + arow + ks * 32);
        al[ks] = *reinterpret_cast<const short8v*>(xl + arow + ks * 32);
    }

    // B staging: 960 (n,ch) 16B chunks, global reads row-contiguous
    for (int idx = tid; idx < 960; idx += 256) {
        const int n = idx / 12, ch = idx % 12;
        const size_t g = (size_t)(n0 + n) * 9216 + kb * 96 + ch * 8;
        *reinterpret_cast<short8v*>(&Bs[0][ch][n][0]) =
            *reinterpret_cast<const short8v*>(wph + g);
        *reinterpret_cast<short8v*>(&Bs[1][ch][n][0]) =
            *reinterpret_cast<const short8v*>(wpl + g);
    }
    __syncthreads();

    f32x4 acc[5];
#pragma unroll
    for (int t = 0; t < 5; ++t) acc[t] = (f32x4){0.f, 0.f, 0.f, 0.f};

#pragma unroll
    for (int ks = 0; ks < 3; ++ks) {
        const int ch = ks * 4 + lqw;
#pragma unroll
        for (int t = 0; t < 5; ++t) {
            const short8v bh = *reinterpret_cast<const short8v*>(&Bs[0][ch][t * 16 + l15][0]);
            const short8v bl = *reinterpret_cast<const short8v*>(&Bs[1][ch][t * 16 + l15][0]);
            acc[t] = __builtin_amdgcn_mfma_f32_16x16x32_bf16(ah[ks], bh, acc[t], 0, 0, 0);
            acc[t] = __builtin_amdgcn_mfma_f32_16x16x32_bf16(ah[ks], bl, acc[t], 0, 0, 0);
            acc[t] = __builtin_amdgcn_mfma_f32_16x16x32_bf16(al[ks], bh, acc[t], 0, 0, 0);
        }
    }

    const int crow0 = mt * 64 + w * 16 + lqw * 4;
#pragma unroll
    for (int t = 0; t < 5; ++t) {
#pragma unroll
        for (int v = 0; v < 4; ++v) {
            s_part[((size_t)kb * 256 + crow0 + v) * 160 + n0 + t * 16 + l15] = acc[t][v];
        }
    }

    // ---- fused reduce: last 256 finishers do the per-b squash ----
    __threadfence();                       // make s_part stores device-visible
    if (tid == 0) tkt = atomicAdd(cnt, 1u);
    __syncthreads();
    const unsigned t_ = tkt;
    if (t_ < 512u) return;
    if (tid == 0) spin_until(cnt, 768u);
    __syncthreads();
    __threadfence();                       // acquire: see all s_part stores

    if (mode == 0) {
        const int b = (int)t_ - 512;
        const int n = tid;
        if (n < 160) {
            const float* p = s_part + (size_t)b * 160 + n;
            float s0 = 0.f, s1 = 0.f, s2 = 0.f, s3 = 0.f,
                  s4 = 0.f, s5 = 0.f, s6 = 0.f, s7 = 0.f;
#pragma unroll
            for (int kv = 0; kv < 96; kv += 8) {
                s0 += p[(size_t)(kv + 0) * 40960];
                s1 += p[(size_t)(kv + 1) * 40960];
                s2 += p[(size_t)(kv + 2) * 40960];
                s3 += p[(size_t)(kv + 3) * 40960];
                s4 += p[(size_t)(kv + 4) * 40960];
                s5 += p[(size_t)(kv + 5) * 40960];
                s6 += p[(size_t)(kv + 6) * 40960];
                s7 += p[(size_t)(kv + 7) * 40960];
            }
            const float s = ((s0 + s1) + (s2 + s3)) + ((s4 + s5) + (s6 + s7));
            float sq = s * s;
#pragma unroll
            for (int off = 1; off < 16; off <<= 1) sq += __shfl_xor(sq, off, 16);
            const float scale = (sq / (1.f + sq)) / sqrtf(sq + 1e-9f);
            const float val = s * scale;
            const unsigned short h = f2bf(val);
            vTh[n * 256 + b] = h;
            vTl[n * 256 + b] = f2bf(val - bf2f(h));
        }
    } else {
        const int eb = (int)t_ - 512;
        if (eb < 160) {
            const int e = eb * 256 + tid;
            float s0 = 0.f, s1 = 0.f, s2 = 0.f, s3 = 0.f;
#pragma unroll
            for (int kv = 0; kv < 96; kv += 4) {
                s0 += s_part[(size_t)(kv + 0) * 40960 + e];
                s1 += s_part[(size_t)(kv + 1) * 40960 + e];
                s2 += s_part[(size_t)(kv + 2) * 40960 + e];
                s3 += s_part[(size_t)(kv + 3) * 40960 + e];
            }
            const float s = (s0 + s1) + (s2 + s3);
            float sq = s * s;
#pragma unroll
            for (int off = 1; off < 16; off <<= 1) sq += __shfl_xor(sq, off, 16);
            const float scale = (sq / (1.f + sq)) / sqrtf(sq + 1e-9f);
            vout[e] = s * scale;
        }
    }
}

// ---------------------------------------------------------------------------
// k_aMs: k_aM with fused softmax via last-finisher tickets (last 10 of 1152
// blocks; block=128 matches the softmax shape). All blocks co-resident.
__global__ __launch_bounds__(128) void k_aMs(const unsigned short* __restrict__ vTh,
                                             const unsigned short* __restrict__ vTl,
                                             const unsigned short* __restrict__ xTh,
                                             const unsigned short* __restrict__ xTl,
                                             const float* __restrict__ W,
                                             float* __restrict__ dbp,
                                             const float* __restrict__ bprev, // null -> 0
                                             float* __restrict__ bnew,
                                             float* __restrict__ cij,
                                             unsigned* __restrict__ cnt)
{
    __shared__ float dbl[20];
    __shared__ unsigned tkt;
    __shared__ float red[2];
    __shared__ float red2[2];
    const int mt = blockIdx.x >> 1;
    const int kh = blockIdx.x & 1;
    const int m0 = mt * 16;
    const int r0 = m0 >> 3;
    const int b0 = kh * 128;
    const int tid  = threadIdx.x;
    const int w    = tid >> 6;
    const int lane = tid & 63;
    const int l15  = lane & 15;
    const int lqw  = lane >> 4;
    if (tid < 20) dbl[tid] = 0.f;

    const size_t xbase = (size_t)(m0 + l15) * 256 + b0 + lqw * 8;

    f32x4 acc[5];
#pragma unroll
    for (int t = 0; t < 5; ++t) acc[t] = (f32x4){0.f, 0.f, 0.f, 0.f};

#pragma unroll
    for (int ks = 0; ks < 4; ++ks) {
        const short8v bh = *reinterpret_cast<const short8v*>(xTh + xbase + ks * 32);
        const short8v bl = *reinterpret_cast<const short8v*>(xTl + xbase + ks * 32);
#pragma unroll
        for (int t = 0; t < 5; ++t) {
            const size_t vbase = (size_t)(w * 80 + t * 16 + l15) * 256 + b0 + lqw * 8 + ks * 32;
            const short8v ah = *reinterpret_cast<const short8v*>(vTh + vbase);
            const short8v al = *reinterpret_cast<const short8v*>(vTl + vbase);
            acc[t] = __builtin_amdgcn_mfma_f32_16x16x32_bf16(ah, bh, acc[t], 0, 0, 0);
            acc[t] = __builtin_amdgcn_mfma_f32_16x16x32_bf16(ah, bl, acc[t], 0, 0, 0);
            acc[t] = __builtin_amdgcn_mfma_f32_16x16x32_bf16(al, bh, acc[t], 0, 0, 0);
        }
    }

    __syncthreads();   // dbl init visible
    const int rloc = l15 >> 3;
    const int i = l15 & 7;
    const int r = r0 + rloc;
#pragma unroll
    for (int t = 0; t < 5; ++t) {
        const int c = w * 5 + t;
        const float* wp = &W[(((size_t)(r * 10 + c) * 16 + lqw * 4) * 8) + i];
        float pv = wp[0] * acc[t][0] + wp[8] * acc[t][1] + wp[16] * acc[t][2] + wp[24] * acc[t][3];
        pv += __shfl_xor(pv, 16);
        pv += __shfl_xor(pv, 32);
        pv += __shfl_xor(pv, 1);
        pv += __shfl_xor(pv, 2);
        pv += __shfl_xor(pv, 4);
        if ((lane & 55) == 0)            // lanes 0 (r0) and 8 (r0+1)
            dbl[rloc * 10 + c] = pv;
    }
    __syncthreads();
    if (tid < 20) dbp[(size_t)kh * 11520 + (r0 + tid / 10) * 10 + (tid % 10)] = dbl[tid];

    // ---- fused softmax: last 10 finishers each handle one cap column ----
    __threadfence();
    if (tid == 0) tkt = atomicAdd(cnt, 1u);
    __syncthreads();
    const unsigned t_ = tkt;
    if (t_ < 1142u) return;
    if (tid == 0) spin_until(cnt, 1152u);
    __syncthreads();
    __threadfence();

    const int c = (int)t_ - 1142;
    float bv[9];
#pragma unroll
    for (int jj = 0; jj < 9; ++jj) {
        const int idx = (tid + jj * 128) * 10 + c;
        const float d = dbp[idx] + dbp[11520 + idx];
        bv[jj] = (bprev ? bprev[idx] : 0.f) + d * (1.0f / 256.0f);
    }
    float mx = bv[0];
#pragma unroll
    for (int jj = 1; jj < 9; ++jj) mx = fmaxf(mx, bv[jj]);
#pragma unroll
    for (int off = 1; off < 64; off <<= 1) mx = fmaxf(mx, __shfl_xor(mx, off, 64));
    if ((tid & 63) == 0) red[tid >> 6] = mx;
    __syncthreads();
    mx = fmaxf(red[0], red[1]);
    float es[9], lsum = 0.f;
#pragma unroll
    for (int jj = 0; jj < 9; ++jj) { es[jj] = expf(bv[jj] - mx); lsum += es[jj]; }
#pragma unroll
    for (int off = 1; off < 64; off <<= 1) lsum += __shfl_xor(lsum, off, 64);
    if ((tid & 63) == 0) red2[tid >> 6] = lsum;
    __syncthreads();
    const float inv = 1.f / (red2[0] + red2[1]);
#pragma unroll
    for (int jj = 0; jj < 9; ++jj) {
        const int idx = (tid + jj * 128) * 10 + c;
        bnew[idx] = bv[jj];
        cij[idx] = es[jj] * inv;
    }
}

// ---------------------------------------------------------------------------
// k_scale2: wp{h,l}[n][k] = bf16_split( cij[r][c] * W[r][c][o][i] )
__global__ __launch_bounds__(256) void k_scale2(const float* __restrict__ W,
                                                const float* __restrict__ cw,
                                                unsigned short* __restrict__ wph,
                                                unsigned short* __restrict__ wpl)
{
    __shared__ float raw[2560];
    __shared__ float cl[20];
    const int r0 = blockIdx.x * 2;
    const int tid = threadIdx.x;
    if (tid < 20) cl[tid] = cw[r0 * 10 + tid];
    const float4* __restrict__ W4 = reinterpret_cast<const float4*>(W) + (size_t)r0 * 320;
#pragma unroll
    for (int q = 0; q < 3; ++q) {
        const int idx = q * 256 + tid;
        if (idx < 640) *reinterpret_cast<float4*>(&raw[idx * 4]) = W4[idx];
    }
    __syncthreads();
#pragma unroll
    for (int q = 0; q < 10; ++q) {
        const int idx = q * 256 + tid;           // 0..2559
        const int n = idx >> 4, kloc = idx & 15;
        const int rl = kloc >> 3, i = kloc & 7, c = n >> 4, o = n & 15;
        const float wv = raw[rl * 1280 + c * 128 + o * 8 + i] * cl[rl * 10 + c];
        const unsigned short h = f2bf(wv);
        const size_t off = (size_t)n * 9216 + r0 * 8 + kloc;
        wph[off] = h;
        wpl[off] = f2bf(wv - bf2f(h));
    }
}

// ---------------------------------------------------------------------------
// k_sc2c: blocks 0..575 = k_scale2(c3); blocks 576..3455 broadcast c3 -> out.
__global__ __launch_bounds__(256) void k_sc2c(const float* __restrict__ W,
                                              const float* __restrict__ cw,
                                              unsigned short* __restrict__ wph,
                                              unsigned short* __restrict__ wpl,
                                              float* __restrict__ out)
{
    const int tid = threadIdx.x;
    if (blockIdx.x < 576) {
        __shared__ float raw[2560];
        __shared__ float cl[20];
        const int r0 = blockIdx.x * 2;
        if (tid < 20) cl[tid] = cw[r0 * 10 + tid];
        const float4* __restrict__ W4 = reinterpret_cast<const float4*>(W) + (size_t)r0 * 320;
#pragma unroll
        for (int q = 0; q < 3; ++q) {
            const int idx = q * 256 + tid;
            if (idx < 640) *reinterpret_cast<float4*>(&raw[idx * 4]) = W4[idx];
        }
        __syncthreads();
#pragma unroll
        for (int q = 0; q < 10; ++q) {
            const int idx = q * 256 + tid;
            const int n = idx >> 4, kloc = idx & 15;
            const int rl = kloc >> 3, i = kloc & 7, c = n >> 4, o = n & 15;
            const float wv = raw[rl * 1280 + c * 128 + o * 8 + i] * cl[rl * 10 + c];
            const unsigned short h = f2bf(wv);
            const size_t off = (size_t)n * 9216 + r0 * 8 + kloc;
            wph[off] = h;
            wpl[off] = f2bf(wv - bf2f(h));
        }
    } else {
        const int i = (blockIdx.x - 576) * 256 + tid;   // 0..737279 float4
        const float4 v = reinterpret_cast<const float4*>(cw)[i % 2880];
        reinterpret_cast<float4*>(out + 40960)[i] = v;
    }
}

// ---------------------------------------------------------------------------
extern "C" void kernel_launch(void* const* d_in, const int* in_sizes, int n_in,
                              void* d_out, int out_size, void* d_ws, size_t ws_size,
                              hipStream_t stream)
{
    const float* x = (const float*)d_in[0];
    const float* W = (const float*)d_in[1];
    float* out = (float*)d_out;

    unsigned short* xh  = (unsigned short*)d_ws;      // 2359296 shorts each
    unsigned short* xl  = xh + 2359296;
    unsigned short* xTh = xl + 2359296;
    unsigned short* xTl = xTh + 2359296;
    unsigned short* wph = xTl + 2359296;              // 1474560 shorts each
    unsigned short* wpl = wph + 1474560;
    unsigned short* vTh = wpl + 1474560;              // 40960 shorts each
    unsigned short* vTl = vTh + 40960;
    float* s_part = (float*)(vTl + 40960 + 32);       // 96*40960 f32 (aligned pad)
    float* b1   = s_part + 3932160;
    float* b2   = b1 + 11520;
    float* c2   = b2 + 11520;
    float* c3   = c2 + 11520;
    float* dbp0 = c3 + 11520;
    float* dbp1 = dbp0 + 23040;
    unsigned* cnts = (unsigned*)(dbp1 + 23040);       // 8 ticket counters

    // prep: x splits + iteration-1 const W' + counter zeroing
    k_prep<<<3456, 256, 0, stream>>>(x, W, xh, xl, wph, wpl, xTh, xTl, cnts);

    // ---- iteration 1 ----
    k_sMr<<<768, 256, 0, stream>>>(xh, xl, wph, wpl, s_part, vTh, vTl, out, 0, cnts + 0);
    k_aMs<<<1152, 128, 0, stream>>>(vTh, vTl, xTh, xTl, W, dbp0, nullptr, b1, c2, cnts + 1);
    k_scale2<<<576, 256, 0, stream>>>(W, c2, wph, wpl);

    // ---- iteration 2 ----
    k_sMr<<<768, 256, 0, stream>>>(xh, xl, wph, wpl, s_part, vTh, vTl, out, 0, cnts + 2);
    k_aMs<<<1152, 128, 0, stream>>>(vTh, vTl, xTh, xTl, W, dbp1, b1, b2, c3, cnts + 3);
    k_sc2c<<<3456, 256, 0, stream>>>(W, c3, wph, wpl, out);

    // ---- iteration 3: GEMM + fused squash -> out ----
    k_sMr<<<768, 256, 0, stream>>>(xh, xl, wph, wpl, s_part, vTh, vTl, out, 1, cnts + 4);
}

// Round 16
// 111.896 us; speedup vs baseline: 5.1735x; 5.1735x over previous
//
#include <hip/hip_runtime.h>
#include <math.h>

// Capsule routing, fused. Both GEMMs via bf16 hi/lo-split MFMA (hh+hl+lh).
// x: [256][9216] f32   W: [1152][10][16][8] f32
// out: v [256][10][16] (40960) then c_out broadcast [256][1152][10] (2949120)
// 11 launches. W' = c∘W scale+bf16-split fused into k_sM's B-staging (bytes
// staged are identical to the precomputed-wp version; no extra traffic).

typedef __attribute__((ext_vector_type(8))) short short8v;
typedef __attribute__((ext_vector_type(4))) float f32x4;

__device__ __forceinline__ unsigned short f2bf(float f) {
    unsigned u = __float_as_uint(f);
    u += 0x7FFFu + ((u >> 16) & 1u);          // round-to-nearest-even
    return (unsigned short)(u >> 16);
}
__device__ __forceinline__ float bf2f(unsigned short h) {
    return __uint_as_float(((unsigned)h) << 16);
}

// ---------------------------------------------------------------------------
// k_prep: bid<2304: x -> bf16 hi/lo (row-major [b][k]).
//         2304..2879: xT hi/lo [m=9216][b=256] via LDS transpose.
__global__ __launch_bounds__(256) void k_prep(const float* __restrict__ x,
                                              unsigned short* __restrict__ xh,
                                              unsigned short* __restrict__ xl,
                                              unsigned short* __restrict__ xTh,
                                              unsigned short* __restrict__ xTl)
{
    const int tid = threadIdx.x;
    if (blockIdx.x < 2304) {
        const int i = blockIdx.x * 256 + tid;   // float4 index, 589824 total
        const float4 v = reinterpret_cast<const float4*>(x)[i];
        const unsigned short h0 = f2bf(v.x), h1 = f2bf(v.y), h2 = f2bf(v.z), h3 = f2bf(v.w);
        const unsigned short l0 = f2bf(v.x - bf2f(h0)), l1 = f2bf(v.y - bf2f(h1)),
                             l2 = f2bf(v.z - bf2f(h2)), l3 = f2bf(v.w - bf2f(h3));
        reinterpret_cast<uint2*>(xh)[i] =
            make_uint2((unsigned)h0 | ((unsigned)h1 << 16), (unsigned)h2 | ((unsigned)h3 << 16));
        reinterpret_cast<uint2*>(xl)[i] =
            make_uint2((unsigned)l0 | ((unsigned)l1 << 16), (unsigned)l2 | ((unsigned)l3 << 16));
    } else {
        // xT transpose+split: m-chunk of 16, all 256 b.
        __shared__ short Th[16][256];
        __shared__ short Tl[16][256];
        const int m0 = (blockIdx.x - 2304) * 16;
        const int b = tid;
#pragma unroll
        for (int q = 0; q < 4; ++q) {
            const float4 v = reinterpret_cast<const float4*>(x)[(size_t)b * 2304 + (m0 >> 2) + q];
            const unsigned short h0 = f2bf(v.x), h1 = f2bf(v.y), h2 = f2bf(v.z), h3 = f2bf(v.w);
            Th[q * 4 + 0][b] = (short)h0;
            Th[q * 4 + 1][b] = (short)h1;
            Th[q * 4 + 2][b] = (short)h2;
            Th[q * 4 + 3][b] = (short)h3;
            Tl[q * 4 + 0][b] = (short)f2bf(v.x - bf2f(h0));
            Tl[q * 4 + 1][b] = (short)f2bf(v.y - bf2f(h1));
            Tl[q * 4 + 2][b] = (short)f2bf(v.z - bf2f(h2));
            Tl[q * 4 + 3][b] = (short)f2bf(v.w - bf2f(h3));
        }
        __syncthreads();
        const int m = tid >> 4, seg = tid & 15;
        const size_t o = (size_t)(m0 + m) * 256 + seg * 16;
        *reinterpret_cast<uint4*>(xTh + o) = *reinterpret_cast<const uint4*>(&Th[m][seg * 16]);
        *reinterpret_cast<uint4*>(xTh + o + 8) = *reinterpret_cast<const uint4*>(&Th[m][seg * 16 + 8]);
        *reinterpret_cast<uint4*>(xTl + o) = *reinterpret_cast<const uint4*>(&Tl[m][seg * 16]);
        *reinterpret_cast<uint4*>(xTl + o + 8) = *reinterpret_cast<const uint4*>(&Tl[m][seg * 16 + 8]);
    }
}

// ---------------------------------------------------------------------------
// k_sM (v2 + XCD swizzle + inline W'-scale): s_part[kb][b][n] =
// sum_{k in slab} x[b][k] * (cij[r(k)][c(n)] * W[k][n]).
// grid 768; work = kb(96) x mt(4) x nt(2); block 256 = 4 waves; 30.7 KB LDS.
// Swizzle: kb = (j%12)*8 + (bid&7) — all 8 workers of a kb on one XCD, so the
// raw-W slab is L2-hot after the first toucher. B-staging loads raw f32 W
// (32 B/chunk, same bytes as the old bf16 hi+lo pair), scales by cij,
// RNE-splits to hi/lo — arithmetic identical to the old k_scale2+wp path.
__global__ __launch_bounds__(256) void k_sM(const unsigned short* __restrict__ xh,
                                            const unsigned short* __restrict__ xl,
                                            const float* __restrict__ W,
                                            const float* __restrict__ cw, // null -> 1/1152
                                            float* __restrict__ s_part)
{
    __shared__ alignas(16) short Bs[2][12][80][8];   // 30720 B
    __shared__ float cl[120];                        // cij for this kb's 12 routes
    const int bid  = blockIdx.x;
    const int xcd  = bid & 7;
    const int j    = bid >> 3;            // 0..95
    const int kb   = (j % 12) * 8 + xcd;  // 0..95
    const int mtnt = j / 12;              // 0..7
    const int mt = mtnt >> 1;
    const int nt = mtnt & 1;
    const int tid  = threadIdx.x;
    const int w    = tid >> 6;
    const int lane = tid & 63;
    const int l15  = lane & 15;
    const int lqw  = lane >> 4;
    const int row  = mt * 64 + w * 16 + l15;
    const int n0   = nt * 80;
    const int r_base = kb * 12;

    // A prefetch (6 global loads; latency hides under B staging + barrier)
    short8v ah[3], al[3];
    const size_t arow = (size_t)row * 9216 + kb * 96 + lqw * 8;
#pragma unroll
    for (int ks = 0; ks < 3; ++ks) {
        ah[ks] = *reinterpret_cast<const short8v*>(xh + arow + ks * 32);
        al[ks] = *reinterpret_cast<const short8v*>(xl + arow + ks * 32);
    }

    // stage cij for the slab's 12 routes
    if (tid < 120) cl[tid] = cw ? cw[r_base * 10 + tid] : (1.0f / 1152.0f);
    __syncthreads();

    // B staging with inline scale+split: chunk (n, ch); GLOBAL column gn = n0+n.
    // W[r_base+ch][c][o][0..7] is 32 B contiguous raw; c = gn>>4, o = gn&15.
    for (int idx = tid; idx < 960; idx += 256) {
        const int n = idx / 12, ch = idx % 12;
        const int gn = n0 + n;                // FIX (R15 bug): global column
        const int c = gn >> 4, o = gn & 15;
        const float sc = cl[ch * 10 + c];
        const float* wp = &W[(size_t)(r_base + ch) * 1280 + c * 128 + o * 8];
        const float4 w0 = *reinterpret_cast<const float4*>(wp);
        const float4 w1 = *reinterpret_cast<const float4*>(wp + 4);
        float v[8] = { w0.x * sc, w0.y * sc, w0.z * sc, w0.w * sc,
                       w1.x * sc, w1.y * sc, w1.z * sc, w1.w * sc };
        short8v hv, lv;
#pragma unroll
        for (int q = 0; q < 8; ++q) {
            const unsigned short h = f2bf(v[q]);
            hv[q] = (short)h;
            lv[q] = (short)f2bf(v[q] - bf2f(h));
        }
        *reinterpret_cast<short8v*>(&Bs[0][ch][n][0]) = hv;
        *reinterpret_cast<short8v*>(&Bs[1][ch][n][0]) = lv;
    }
    __syncthreads();

    f32x4 acc[5];
#pragma unroll
    for (int t = 0; t < 5; ++t) acc[t] = (f32x4){0.f, 0.f, 0.f, 0.f};

#pragma unroll
    for (int ks = 0; ks < 3; ++ks) {
        const int ch = ks * 4 + lqw;
#pragma unroll
        for (int t = 0; t < 5; ++t) {
            const short8v bh = *reinterpret_cast<const short8v*>(&Bs[0][ch][t * 16 + l15][0]);
            const short8v bl = *reinterpret_cast<const short8v*>(&Bs[1][ch][t * 16 + l15][0]);
            acc[t] = __builtin_amdgcn_mfma_f32_16x16x32_bf16(ah[ks], bh, acc[t], 0, 0, 0);
            acc[t] = __builtin_amdgcn_mfma_f32_16x16x32_bf16(ah[ks], bl, acc[t], 0, 0, 0);
            acc[t] = __builtin_amdgcn_mfma_f32_16x16x32_bf16(al[ks], bh, acc[t], 0, 0, 0);
        }
    }

    const int crow0 = mt * 64 + w * 16 + lqw * 4;
#pragma unroll
    for (int t = 0; t < 5; ++t) {
#pragma unroll
        for (int v = 0; v < 4; ++v) {
            s_part[((size_t)kb * 256 + crow0 + v) * 160 + n0 + t * 16 + l15] = acc[t][v];
        }
    }
}

// ---------------------------------------------------------------------------
// k_rvT: v[b][n] = squash(sum_kb s_part) -> write bf16 hi/lo TRANSPOSED vT[n][b].
// grid 256 (one b per block), block 192 (160 active = n).
__global__ __launch_bounds__(192) void k_rvT(const float* __restrict__ s_part,
                                             unsigned short* __restrict__ vTh,
                                             unsigned short* __restrict__ vTl)
{
    const int b = blockIdx.x;
    const int n = threadIdx.x;
    if (n < 160) {
        const float* p = s_part + (size_t)b * 160 + n;
        float s0 = 0.f, s1 = 0.f, s2 = 0.f, s3 = 0.f, s4 = 0.f, s5 = 0.f, s6 = 0.f, s7 = 0.f;
#pragma unroll
        for (int kbv = 0; kbv < 96; kbv += 8) {
            s0 += p[(size_t)(kbv + 0) * 40960];
            s1 += p[(size_t)(kbv + 1) * 40960];
            s2 += p[(size_t)(kbv + 2) * 40960];
            s3 += p[(size_t)(kbv + 3) * 40960];
            s4 += p[(size_t)(kbv + 4) * 40960];
            s5 += p[(size_t)(kbv + 5) * 40960];
            s6 += p[(size_t)(kbv + 6) * 40960];
            s7 += p[(size_t)(kbv + 7) * 40960];
        }
        const float s = ((s0 + s1) + (s2 + s3)) + ((s4 + s5) + (s6 + s7));
        float sq = s * s;
#pragma unroll
        for (int off = 1; off < 16; off <<= 1) sq += __shfl_xor(sq, off, 16);
        const float scale = (sq / (1.f + sq)) / sqrtf(sq + 1e-9f);
        const float val = s * scale;
        const unsigned short h = f2bf(val);
        vTh[n * 256 + b] = h;
        vTl[n * 256 + b] = f2bf(val - bf2f(h));
    }
}

// ---------------------------------------------------------------------------
// k_aM: agreement via MFMA. T^T = vT(160x256) x x(256x9216); then
// dbp[kh][r][c] = sum_{i,o} W[r][c][o][i] * T[m=r*8+i][n=c*16+o].
// grid 1152 = mt(576, 16 m = 2 routes) x kh(2, 128-batch halves); block 128.
__global__ __launch_bounds__(128) void k_aM(const unsigned short* __restrict__ vTh,
                                            const unsigned short* __restrict__ vTl,
                                            const unsigned short* __restrict__ xTh,
                                            const unsigned short* __restrict__ xTl,
                                            const float* __restrict__ W,
                                            float* __restrict__ dbp)
{
    __shared__ float dbl[20];
    const int mt = blockIdx.x >> 1;
    const int kh = blockIdx.x & 1;
    const int m0 = mt * 16;
    const int r0 = m0 >> 3;
    const int b0 = kh * 128;
    const int tid  = threadIdx.x;
    const int w    = tid >> 6;
    const int lane = tid & 63;
    const int l15  = lane & 15;
    const int lqw  = lane >> 4;
    if (tid < 20) dbl[tid] = 0.f;

    const size_t xbase = (size_t)(m0 + l15) * 256 + b0 + lqw * 8;

    f32x4 acc[5];
#pragma unroll
    for (int t = 0; t < 5; ++t) acc[t] = (f32x4){0.f, 0.f, 0.f, 0.f};

#pragma unroll
    for (int ks = 0; ks < 4; ++ks) {
        const short8v bh = *reinterpret_cast<const short8v*>(xTh + xbase + ks * 32);
        const short8v bl = *reinterpret_cast<const short8v*>(xTl + xbase + ks * 32);
#pragma unroll
        for (int t = 0; t < 5; ++t) {
            const size_t vbase = (size_t)(w * 80 + t * 16 + l15) * 256 + b0 + lqw * 8 + ks * 32;
            const short8v ah = *reinterpret_cast<const short8v*>(vTh + vbase);
            const short8v al = *reinterpret_cast<const short8v*>(vTl + vbase);
            acc[t] = __builtin_amdgcn_mfma_f32_16x16x32_bf16(ah, bh, acc[t], 0, 0, 0);
            acc[t] = __builtin_amdgcn_mfma_f32_16x16x32_bf16(ah, bl, acc[t], 0, 0, 0);
            acc[t] = __builtin_amdgcn_mfma_f32_16x16x32_bf16(al, bh, acc[t], 0, 0, 0);
        }
    }

    __syncthreads();   // dbl init visible
    const int rloc = l15 >> 3;
    const int i = l15 & 7;
    const int r = r0 + rloc;
#pragma unroll
    for (int t = 0; t < 5; ++t) {
        const int c = w * 5 + t;
        const float* wp = &W[(((size_t)(r * 10 + c) * 16 + lqw * 4) * 8) + i];
        float pv = wp[0] * acc[t][0] + wp[8] * acc[t][1] + wp[16] * acc[t][2] + wp[24] * acc[t][3];
        pv += __shfl_xor(pv, 16);
        pv += __shfl_xor(pv, 32);
        pv += __shfl_xor(pv, 1);
        pv += __shfl_xor(pv, 2);
        pv += __shfl_xor(pv, 4);
        if ((lane & 55) == 0)            // lanes 0 (r0) and 8 (r0+1)
            dbl[rloc * 10 + c] = pv;
    }
    __syncthreads();
    if (tid < 20) dbp[(size_t)kh * 11520 + (r0 + tid / 10) * 10 + (tid % 10)] = dbl[tid];
}

// ---------------------------------------------------------------------------
// k_sm: bnew = bprev + (sum of 2 dbp parts)/256 ; c = softmax over routes
__global__ __launch_bounds__(128) void k_sm(const float* __restrict__ bprev,
                                            const float* __restrict__ dbp,
                                            float* __restrict__ bnew,
                                            float* __restrict__ cij)
{
    __shared__ float red[2];
    __shared__ float red2[2];
    const int c = blockIdx.x;
    const int tid = threadIdx.x;
    float bv[9];
#pragma unroll
    for (int j = 0; j < 9; ++j) {
        const int idx = (tid + j * 128) * 10 + c;
        const float d = dbp[idx] + dbp[11520 + idx];
        bv[j] = (bprev ? bprev[idx] : 0.f) + d * (1.0f / 256.0f);
    }
    float mx = bv[0];
#pragma unroll
    for (int j = 1; j < 9; ++j) mx = fmaxf(mx, bv[j]);
#pragma unroll
    for (int off = 1; off < 64; off <<= 1) mx = fmaxf(mx, __shfl_xor(mx, off, 64));
    if ((tid & 63) == 0) red[tid >> 6] = mx;
    __syncthreads();
    mx = fmaxf(red[0], red[1]);
    float es[9], lsum = 0.f;
#pragma unroll
    for (int j = 0; j < 9; ++j) { es[j] = expf(bv[j] - mx); lsum += es[j]; }
#pragma unroll
    for (int off = 1; off < 64; off <<= 1) lsum += __shfl_xor(lsum, off, 64);
    if ((tid & 63) == 0) red2[tid >> 6] = lsum;
    __syncthreads();
    const float inv = 1.f / (red2[0] + red2[1]);
#pragma unroll
    for (int j = 0; j < 9; ++j) {
        const int idx = (tid + j * 128) * 10 + c;
        bnew[idx] = bv[j];
        cij[idx] = es[j] * inv;
    }
}

// ---------------------------------------------------------------------------
// k_rvc: blocks 0..159 reduce+squash s_part -> out v; blocks 160.. broadcast c3.
__global__ __launch_bounds__(256) void k_rvc(const float* __restrict__ s_part,
                                             const float* __restrict__ cij,
                                             float* __restrict__ out)
{
    const int tid = threadIdx.x;
    if (blockIdx.x < 160) {
        const int e = blockIdx.x * 256 + tid;
        float s0 = 0.f, s1 = 0.f, s2 = 0.f, s3 = 0.f;
#pragma unroll
        for (int kbv = 0; kbv < 96; kbv += 4) {
            s0 += s_part[(size_t)(kbv + 0) * 40960 + e];
            s1 += s_part[(size_t)(kbv + 1) * 40960 + e];
            s2 += s_part[(size_t)(kbv + 2) * 40960 + e];
            s3 += s_part[(size_t)(kbv + 3) * 40960 + e];
        }
        const float s = (s0 + s1) + (s2 + s3);
        float sq = s * s;
#pragma unroll
        for (int off = 1; off < 16; off <<= 1) sq += __shfl_xor(sq, off, 16);
        const float scale = (sq / (1.f + sq)) / sqrtf(sq + 1e-9f);
        out[e] = s * scale;
    } else {
        const int i = (blockIdx.x - 160) * 256 + tid;   // 0..737279 float4
        const float4 v = reinterpret_cast<const float4*>(cij)[i % 2880];
        reinterpret_cast<float4*>(out + 40960)[i] = v;
    }
}

// ---------------------------------------------------------------------------
extern "C" void kernel_launch(void* const* d_in, const int* in_sizes, int n_in,
                              void* d_out, int out_size, void* d_ws, size_t ws_size,
                              hipStream_t stream)
{
    const float* x = (const float*)d_in[0];
    const float* W = (const float*)d_in[1];
    float* out = (float*)d_out;

    unsigned short* xh  = (unsigned short*)d_ws;      // 2359296 shorts each
    unsigned short* xl  = xh + 2359296;
    unsigned short* xTh = xl + 2359296;
    unsigned short* xTl = xTh + 2359296;
    unsigned short* vTh = xTl + 2359296;              // 40960 shorts each
    unsigned short* vTl = vTh + 40960;
    float* s_part = (float*)(vTl + 40960 + 32);       // 96*40960 f32 (aligned pad)
    float* b1   = s_part + 3932160;
    float* b2   = b1 + 11520;
    float* c2   = b2 + 11520;
    float* c3   = c2 + 11520;
    float* dbp0 = c3 + 11520;
    float* dbp1 = dbp0 + 23040;

    // prep: x hi/lo split (row-major + transposed)
    k_prep<<<2880, 256, 0, stream>>>(x, xh, xl, xTh, xTl);

    // ---- iteration 1 (c uniform = 1/1152, inline in k_sM) ----
    k_sM<<<768, 256, 0, stream>>>(xh, xl, W, nullptr, s_part);
    k_rvT<<<256, 192, 0, stream>>>(s_part, vTh, vTl);
    k_aM<<<1152, 128, 0, stream>>>(vTh, vTl, xTh, xTl, W, dbp0);
    k_sm<<<10, 128, 0, stream>>>(nullptr, dbp0, b1, c2);

    // ---- iteration 2 ----
    k_sM<<<768, 256, 0, stream>>>(xh, xl, W, c2, s_part);
    k_rvT<<<256, 192, 0, stream>>>(s_part, vTh, vTl);
    k_aM<<<1152, 128, 0, stream>>>(vTh, vTl, xTh, xTl, W, dbp1);
    k_sm<<<10, 128, 0, stream>>>(b1, dbp1, b2, c3);

    // ---- iteration 3 + outputs ----
    k_sM<<<768, 256, 0, stream>>>(xh, xl, W, c3, s_part);
    k_rvc<<<3040, 256, 0, stream>>>(s_part, c3, out);
}

// Round 17
// 110.265 us; speedup vs baseline: 5.2500x; 1.0148x over previous
//
#include <hip/hip_runtime.h>
#include <math.h>

// Capsule routing, fused. Both GEMMs via bf16 hi/lo-split MFMA (hh+hl+lh).
// x: [256][9216] f32   W: [1152][10][16][8] f32
// out: v [256][10][16] (40960) then c_out broadcast [256][1152][10] (2949120)
// 11 launches; xT-transpose and c_out-broadcast ride as independent tail
// blocks of k_sM launches (overlap the GEMM instead of serializing).

typedef __attribute__((ext_vector_type(8))) short short8v;
typedef __attribute__((ext_vector_type(4))) float f32x4;

__device__ __forceinline__ unsigned short f2bf(float f) {
    unsigned u = __float_as_uint(f);
    u += 0x7FFFu + ((u >> 16) & 1u);          // round-to-nearest-even
    return (unsigned short)(u >> 16);
}
__device__ __forceinline__ float bf2f(unsigned short h) {
    return __uint_as_float(((unsigned)h) << 16);
}

// ---------------------------------------------------------------------------
// k_prep: x -> bf16 hi/lo (row-major [b][k]). grid 2304.
__global__ __launch_bounds__(256) void k_prep(const float* __restrict__ x,
                                              unsigned short* __restrict__ xh,
                                              unsigned short* __restrict__ xl)
{
    const int tid = threadIdx.x;
    const int i = blockIdx.x * 256 + tid;   // float4 index, 589824 total
    const float4 v = reinterpret_cast<const float4*>(x)[i];
    const unsigned short h0 = f2bf(v.x), h1 = f2bf(v.y), h2 = f2bf(v.z), h3 = f2bf(v.w);
    const unsigned short l0 = f2bf(v.x - bf2f(h0)), l1 = f2bf(v.y - bf2f(h1)),
                         l2 = f2bf(v.z - bf2f(h2)), l3 = f2bf(v.w - bf2f(h3));
    reinterpret_cast<uint2*>(xh)[i] =
        make_uint2((unsigned)h0 | ((unsigned)h1 << 16), (unsigned)h2 | ((unsigned)h3 << 16));
    reinterpret_cast<uint2*>(xl)[i] =
        make_uint2((unsigned)l0 | ((unsigned)l1 << 16), (unsigned)l2 | ((unsigned)l3 << 16));
}

// ---------------------------------------------------------------------------
// Shared-memory union: GEMM staging vs transpose-tail staging (keeps 31 KB).
union ShMem {
    struct { alignas(16) short Bs[2][12][80][8]; float cl[120]; } g;  // 31200 B
    struct { short Th[16][256]; short Tl[16][256]; } t;               // 16384 B
};

// ---------------------------------------------------------------------------
// k_sM (v2 + XCD swizzle + inline W'-scale + independent tails):
// blocks 0..767: s_part[kb][b][n] = sum_{k in slab} x[b][k]*(cij*W)[k][n].
//   grid-work = kb(96) x mt(4) x nt(2); block 256 = 4 waves; LDS 31 KB.
//   Swizzle: kb = (j%12)*8 + (bid&7) — all 8 workers of a kb on one XCD.
// blocks >= 768: tail==1 -> xT hi/lo transpose (prep code, verbatim);
//                tail==2 -> c_out broadcast (bcsrc -> out).
__global__ __launch_bounds__(256) void k_sM(const unsigned short* __restrict__ xh,
                                            const unsigned short* __restrict__ xl,
                                            const float* __restrict__ W,
                                            const float* __restrict__ cw, // null -> 1/1152
                                            float* __restrict__ s_part,
                                            const float* __restrict__ x,
                                            unsigned short* __restrict__ xTh,
                                            unsigned short* __restrict__ xTl,
                                            const float* __restrict__ bcsrc,
                                            float* __restrict__ out,
                                            int tail)
{
    __shared__ ShMem sh;
    const int bid = blockIdx.x;
    const int tid = threadIdx.x;

    if (bid >= 768) {
        if (tail == 1) {
            // xT transpose+split: m-chunk of 16, all 256 b. (verbatim prep)
            const int m0 = (bid - 768) * 16;
            const int b = tid;
#pragma unroll
            for (int q = 0; q < 4; ++q) {
                const float4 v = reinterpret_cast<const float4*>(x)[(size_t)b * 2304 + (m0 >> 2) + q];
                const unsigned short h0 = f2bf(v.x), h1 = f2bf(v.y), h2 = f2bf(v.z), h3 = f2bf(v.w);
                sh.t.Th[q * 4 + 0][b] = (short)h0;
                sh.t.Th[q * 4 + 1][b] = (short)h1;
                sh.t.Th[q * 4 + 2][b] = (short)h2;
                sh.t.Th[q * 4 + 3][b] = (short)h3;
                sh.t.Tl[q * 4 + 0][b] = (short)f2bf(v.x - bf2f(h0));
                sh.t.Tl[q * 4 + 1][b] = (short)f2bf(v.y - bf2f(h1));
                sh.t.Tl[q * 4 + 2][b] = (short)f2bf(v.z - bf2f(h2));
                sh.t.Tl[q * 4 + 3][b] = (short)f2bf(v.w - bf2f(h3));
            }
            __syncthreads();
            const int m = tid >> 4, seg = tid & 15;
            const size_t o = (size_t)(m0 + m) * 256 + seg * 16;
            *reinterpret_cast<uint4*>(xTh + o) = *reinterpret_cast<const uint4*>(&sh.t.Th[m][seg * 16]);
            *reinterpret_cast<uint4*>(xTh + o + 8) = *reinterpret_cast<const uint4*>(&sh.t.Th[m][seg * 16 + 8]);
            *reinterpret_cast<uint4*>(xTl + o) = *reinterpret_cast<const uint4*>(&sh.t.Tl[m][seg * 16]);
            *reinterpret_cast<uint4*>(xTl + o + 8) = *reinterpret_cast<const uint4*>(&sh.t.Tl[m][seg * 16 + 8]);
        } else {
            // c_out broadcast: 2880 blocks x 256 float4 stores
            const int i = (bid - 768) * 256 + tid;
            const float4 v = reinterpret_cast<const float4*>(bcsrc)[i % 2880];
            reinterpret_cast<float4*>(out + 40960)[i] = v;
        }
        return;
    }

    const int xcd  = bid & 7;
    const int j    = bid >> 3;            // 0..95
    const int kb   = (j % 12) * 8 + xcd;  // 0..95
    const int mtnt = j / 12;              // 0..7
    const int mt = mtnt >> 1;
    const int nt = mtnt & 1;
    const int w    = tid >> 6;
    const int lane = tid & 63;
    const int l15  = lane & 15;
    const int lqw  = lane >> 4;
    const int row  = mt * 64 + w * 16 + l15;
    const int n0   = nt * 80;
    const int r_base = kb * 12;

    // A prefetch (6 global loads; latency hides under B staging + barrier)
    short8v ah[3], al[3];
    const size_t arow = (size_t)row * 9216 + kb * 96 + lqw * 8;
#pragma unroll
    for (int ks = 0; ks < 3; ++ks) {
        ah[ks] = *reinterpret_cast<const short8v*>(xh + arow + ks * 32);
        al[ks] = *reinterpret_cast<const short8v*>(xl + arow + ks * 32);
    }

    // stage cij for the slab's 12 routes
    if (tid < 120) sh.g.cl[tid] = cw ? cw[r_base * 10 + tid] : (1.0f / 1152.0f);
    __syncthreads();

    // B staging with inline scale+split: chunk (n, ch); GLOBAL column gn = n0+n.
    for (int idx = tid; idx < 960; idx += 256) {
        const int n = idx / 12, ch = idx % 12;
        const int gn = n0 + n;
        const int c = gn >> 4, o = gn & 15;
        const float sc = sh.g.cl[ch * 10 + c];
        const float* wp = &W[(size_t)(r_base + ch) * 1280 + c * 128 + o * 8];
        const float4 w0 = *reinterpret_cast<const float4*>(wp);
        const float4 w1 = *reinterpret_cast<const float4*>(wp + 4);
        float v[8] = { w0.x * sc, w0.y * sc, w0.z * sc, w0.w * sc,
                       w1.x * sc, w1.y * sc, w1.z * sc, w1.w * sc };
        short8v hv, lv;
#pragma unroll
        for (int q = 0; q < 8; ++q) {
            const unsigned short h = f2bf(v[q]);
            hv[q] = (short)h;
            lv[q] = (short)f2bf(v[q] - bf2f(h));
        }
        *reinterpret_cast<short8v*>(&sh.g.Bs[0][ch][n][0]) = hv;
        *reinterpret_cast<short8v*>(&sh.g.Bs[1][ch][n][0]) = lv;
    }
    __syncthreads();

    f32x4 acc[5];
#pragma unroll
    for (int t = 0; t < 5; ++t) acc[t] = (f32x4){0.f, 0.f, 0.f, 0.f};

#pragma unroll
    for (int ks = 0; ks < 3; ++ks) {
        const int ch = ks * 4 + lqw;
#pragma unroll
        for (int t = 0; t < 5; ++t) {
            const short8v bh = *reinterpret_cast<const short8v*>(&sh.g.Bs[0][ch][t * 16 + l15][0]);
            const short8v bl = *reinterpret_cast<const short8v*>(&sh.g.Bs[1][ch][t * 16 + l15][0]);
            acc[t] = __builtin_amdgcn_mfma_f32_16x16x32_bf16(ah[ks], bh, acc[t], 0, 0, 0);
            acc[t] = __builtin_amdgcn_mfma_f32_16x16x32_bf16(ah[ks], bl, acc[t], 0, 0, 0);
            acc[t] = __builtin_amdgcn_mfma_f32_16x16x32_bf16(al[ks], bh, acc[t], 0, 0, 0);
        }
    }

    const int crow0 = mt * 64 + w * 16 + lqw * 4;
#pragma unroll
    for (int t = 0; t < 5; ++t) {
#pragma unroll
        for (int v = 0; v < 4; ++v) {
            s_part[((size_t)kb * 256 + crow0 + v) * 160 + n0 + t * 16 + l15] = acc[t][v];
        }
    }
}

// ---------------------------------------------------------------------------
// k_rvT: v[b][n] = squash(sum_kb s_part) -> write bf16 hi/lo TRANSPOSED vT[n][b].
// grid 256 (one b per block), block 192 (160 active = n).
__global__ __launch_bounds__(192) void k_rvT(const float* __restrict__ s_part,
                                             unsigned short* __restrict__ vTh,
                                             unsigned short* __restrict__ vTl)
{
    const int b = blockIdx.x;
    const int n = threadIdx.x;
    if (n < 160) {
        const float* p = s_part + (size_t)b * 160 + n;
        float s0 = 0.f, s1 = 0.f, s2 = 0.f, s3 = 0.f, s4 = 0.f, s5 = 0.f, s6 = 0.f, s7 = 0.f;
#pragma unroll
        for (int kbv = 0; kbv < 96; kbv += 8) {
            s0 += p[(size_t)(kbv + 0) * 40960];
            s1 += p[(size_t)(kbv + 1) * 40960];
            s2 += p[(size_t)(kbv + 2) * 40960];
            s3 += p[(size_t)(kbv + 3) * 40960];
            s4 += p[(size_t)(kbv + 4) * 40960];
            s5 += p[(size_t)(kbv + 5) * 40960];
            s6 += p[(size_t)(kbv + 6) * 40960];
            s7 += p[(size_t)(kbv + 7) * 40960];
        }
        const float s = ((s0 + s1) + (s2 + s3)) + ((s4 + s5) + (s6 + s7));
        float sq = s * s;
#pragma unroll
        for (int off = 1; off < 16; off <<= 1) sq += __shfl_xor(sq, off, 16);
        const float scale = (sq / (1.f + sq)) / sqrtf(sq + 1e-9f);
        const float val = s * scale;
        const unsigned short h = f2bf(val);
        vTh[n * 256 + b] = h;
        vTl[n * 256 + b] = f2bf(val - bf2f(h));
    }
}

// ---------------------------------------------------------------------------
// k_aM: agreement via MFMA. T^T = vT(160x256) x x(256x9216); then
// dbp[kh][r][c] = sum_{i,o} W[r][c][o][i] * T[m=r*8+i][n=c*16+o].
// grid 1152 = mt(576, 16 m = 2 routes) x kh(2, 128-batch halves); block 128.
__global__ __launch_bounds__(128) void k_aM(const unsigned short* __restrict__ vTh,
                                            const unsigned short* __restrict__ vTl,
                                            const unsigned short* __restrict__ xTh,
                                            const unsigned short* __restrict__ xTl,
                                            const float* __restrict__ W,
                                            float* __restrict__ dbp)
{
    __shared__ float dbl[20];
    const int mt = blockIdx.x >> 1;
    const int kh = blockIdx.x & 1;
    const int m0 = mt * 16;
    const int r0 = m0 >> 3;
    const int b0 = kh * 128;
    const int tid  = threadIdx.x;
    const int w    = tid >> 6;
    const int lane = tid & 63;
    const int l15  = lane & 15;
    const int lqw  = lane >> 4;
    if (tid < 20) dbl[tid] = 0.f;

    const size_t xbase = (size_t)(m0 + l15) * 256 + b0 + lqw * 8;

    f32x4 acc[5];
#pragma unroll
    for (int t = 0; t < 5; ++t) acc[t] = (f32x4){0.f, 0.f, 0.f, 0.f};

#pragma unroll
    for (int ks = 0; ks < 4; ++ks) {
        const short8v bh = *reinterpret_cast<const short8v*>(xTh + xbase + ks * 32);
        const short8v bl = *reinterpret_cast<const short8v*>(xTl + xbase + ks * 32);
#pragma unroll
        for (int t = 0; t < 5; ++t) {
            const size_t vbase = (size_t)(w * 80 + t * 16 + l15) * 256 + b0 + lqw * 8 + ks * 32;
            const short8v ah = *reinterpret_cast<const short8v*>(vTh + vbase);
            const short8v al = *reinterpret_cast<const short8v*>(vTl + vbase);
            acc[t] = __builtin_amdgcn_mfma_f32_16x16x32_bf16(ah, bh, acc[t], 0, 0, 0);
            acc[t] = __builtin_amdgcn_mfma_f32_16x16x32_bf16(ah, bl, acc[t], 0, 0, 0);
            acc[t] = __builtin_amdgcn_mfma_f32_16x16x32_bf16(al, bh, acc[t], 0, 0, 0);
        }
    }

    __syncthreads();   // dbl init visible
    const int rloc = l15 >> 3;
    const int i = l15 & 7;
    const int r = r0 + rloc;
#pragma unroll
    for (int t = 0; t < 5; ++t) {
        const int c = w * 5 + t;
        const float* wp = &W[(((size_t)(r * 10 + c) * 16 + lqw * 4) * 8) + i];
        float pv = wp[0] * acc[t][0] + wp[8] * acc[t][1] + wp[16] * acc[t][2] + wp[24] * acc[t][3];
        pv += __shfl_xor(pv, 16);
        pv += __shfl_xor(pv, 32);
        pv += __shfl_xor(pv, 1);
        pv += __shfl_xor(pv, 2);
        pv += __shfl_xor(pv, 4);
        if ((lane & 55) == 0)            // lanes 0 (r0) and 8 (r0+1)
            dbl[rloc * 10 + c] = pv;
    }
    __syncthreads();
    if (tid < 20) dbp[(size_t)kh * 11520 + (r0 + tid / 10) * 10 + (tid % 10)] = dbl[tid];
}

// ---------------------------------------------------------------------------
// k_sm: bnew = bprev + (sum of 2 dbp parts)/256 ; c = softmax over routes
__global__ __launch_bounds__(128) void k_sm(const float* __restrict__ bprev,
                                            const float* __restrict__ dbp,
                                            float* __restrict__ bnew,
                                            float* __restrict__ cij)
{
    __shared__ float red[2];
    __shared__ float red2[2];
    const int c = blockIdx.x;
    const int tid = threadIdx.x;
    float bv[9];
#pragma unroll
    for (int j = 0; j < 9; ++j) {
        const int idx = (tid + j * 128) * 10 + c;
        const float d = dbp[idx] + dbp[11520 + idx];
        bv[j] = (bprev ? bprev[idx] : 0.f) + d * (1.0f / 256.0f);
    }
    float mx = bv[0];
#pragma unroll
    for (int j = 1; j < 9; ++j) mx = fmaxf(mx, bv[j]);
#pragma unroll
    for (int off = 1; off < 64; off <<= 1) mx = fmaxf(mx, __shfl_xor(mx, off, 64));
    if ((tid & 63) == 0) red[tid >> 6] = mx;
    __syncthreads();
    mx = fmaxf(red[0], red[1]);
    float es[9], lsum = 0.f;
#pragma unroll
    for (int j = 0; j < 9; ++j) { es[j] = expf(bv[j] - mx); lsum += es[j]; }
#pragma unroll
    for (int off = 1; off < 64; off <<= 1) lsum += __shfl_xor(lsum, off, 64);
    if ((tid & 63) == 0) red2[tid >> 6] = lsum;
    __syncthreads();
    const float inv = 1.f / (red2[0] + red2[1]);
#pragma unroll
    for (int j = 0; j < 9; ++j) {
        const int idx = (tid + j * 128) * 10 + c;
        bnew[idx] = bv[j];
        cij[idx] = es[j] * inv;
    }
}

// ---------------------------------------------------------------------------
// k_rv: reduce+squash s_part -> out v (grid 160; c_out handled by k_sM tail).
__global__ __launch_bounds__(256) void k_rv(const float* __restrict__ s_part,
                                            float* __restrict__ out)
{
    const int e = blockIdx.x * 256 + threadIdx.x;
    float s0 = 0.f, s1 = 0.f, s2 = 0.f, s3 = 0.f;
#pragma unroll
    for (int kbv = 0; kbv < 96; kbv += 4) {
        s0 += s_part[(size_t)(kbv + 0) * 40960 + e];
        s1 += s_part[(size_t)(kbv + 1) * 40960 + e];
        s2 += s_part[(size_t)(kbv + 2) * 40960 + e];
        s3 += s_part[(size_t)(kbv + 3) * 40960 + e];
    }
    const float s = (s0 + s1) + (s2 + s3);
    float sq = s * s;
#pragma unroll
    for (int off = 1; off < 16; off <<= 1) sq += __shfl_xor(sq, off, 16);
    const float scale = (sq / (1.f + sq)) / sqrtf(sq + 1e-9f);
    out[e] = s * scale;
}

// ---------------------------------------------------------------------------
extern "C" void kernel_launch(void* const* d_in, const int* in_sizes, int n_in,
                              void* d_out, int out_size, void* d_ws, size_t ws_size,
                              hipStream_t stream)
{
    const float* x = (const float*)d_in[0];
    const float* W = (const float*)d_in[1];
    float* out = (float*)d_out;

    unsigned short* xh  = (unsigned short*)d_ws;      // 2359296 shorts each
    unsigned short* xl  = xh + 2359296;
    unsigned short* xTh = xl + 2359296;
    unsigned short* xTl = xTh + 2359296;
    unsigned short* vTh = xTl + 2359296;              // 40960 shorts each
    unsigned short* vTl = vTh + 40960;
    float* s_part = (float*)(vTl + 40960 + 32);       // 96*40960 f32 (aligned pad)
    float* b1   = s_part + 3932160;
    float* b2   = b1 + 11520;
    float* c2   = b2 + 11520;
    float* c3   = c2 + 11520;
    float* dbp0 = c3 + 11520;
    float* dbp1 = dbp0 + 23040;

    // prep: x hi/lo split (row-major only; transpose rides k_sM it-1 tail)
    k_prep<<<2304, 256, 0, stream>>>(x, xh, xl);

    // ---- iteration 1 (c uniform = 1/1152 inline; tail = xT transpose) ----
    k_sM<<<768 + 576, 256, 0, stream>>>(xh, xl, W, nullptr, s_part,
                                        x, xTh, xTl, nullptr, out, 1);
    k_rvT<<<256, 192, 0, stream>>>(s_part, vTh, vTl);
    k_aM<<<1152, 128, 0, stream>>>(vTh, vTl, xTh, xTl, W, dbp0);
    k_sm<<<10, 128, 0, stream>>>(nullptr, dbp0, b1, c2);

    // ---- iteration 2 ----
    k_sM<<<768, 256, 0, stream>>>(xh, xl, W, c2, s_part,
                                  x, xTh, xTl, nullptr, out, 0);
    k_rvT<<<256, 192, 0, stream>>>(s_part, vTh, vTl);
    k_aM<<<1152, 128, 0, stream>>>(vTh, vTl, xTh, xTl, W, dbp1);
    k_sm<<<10, 128, 0, stream>>>(b1, dbp1, b2, c3);

    // ---- iteration 3 (tail = c_out broadcast) + v squash ----
    k_sM<<<768 + 2880, 256, 0, stream>>>(xh, xl, W, c3, s_part,
                                         x, xTh, xTl, c3, out, 2);
    k_rv<<<160, 256, 0, stream>>>(s_part, out);
}

// Round 18
// 104.878 us; speedup vs baseline: 5.5197x; 1.0514x over previous
//
#include <hip/hip_runtime.h>
#include <math.h>

// Capsule routing, fused. Both GEMMs via bf16 hi/lo-split MFMA (hh+hl+lh).
// x: [256][9216] f32   W: [1152][10][16][8] f32
// out: v [256][10][16] (40960) then c_out broadcast [256][1152][10] (2949120)
// 10 launches. x is consumed in f32 directly by k_sM (hi/lo split in regs —
// same bytes as bf16 h+l, identical numerics); k_prep deleted. xT-transpose
// and c_out-broadcast ride as independent tail blocks of k_sM launches.

typedef __attribute__((ext_vector_type(8))) short short8v;
typedef __attribute__((ext_vector_type(4))) float f32x4;

__device__ __forceinline__ unsigned short f2bf(float f) {
    unsigned u = __float_as_uint(f);
    u += 0x7FFFu + ((u >> 16) & 1u);          // round-to-nearest-even
    return (unsigned short)(u >> 16);
}
__device__ __forceinline__ float bf2f(unsigned short h) {
    return __uint_as_float(((unsigned)h) << 16);
}

// ---------------------------------------------------------------------------
// Shared-memory union: GEMM staging vs transpose-tail staging.
union ShMem {
    struct { alignas(16) short Bs[2][12][80][8]; float cl[120]; } g;  // 31200 B
    struct { short Th[16][256]; short Tl[16][256]; } t;               // 16384 B
};

// ---------------------------------------------------------------------------
// k_sM (XCD swizzle + inline W'-scale + inline x-split + independent tails):
// blocks 0..767: s_part[kb][b][n] = sum_{k in slab} x[b][k]*(cij*W)[k][n].
//   work = kb(96) x mt(4) x nt(2); block 256 = 4 waves; LDS 31 KB.
//   Swizzle: kb = (j%12)*8 + (bid&7) — all 8 workers of a kb on one XCD.
//   A loaded as f32 x (same bytes as bf16 h+l) and RNE-split in registers.
// blocks >= 768: tail==1 -> xT hi/lo transpose; tail==2 -> c_out broadcast.
__global__ __launch_bounds__(256) void k_sM(const float* __restrict__ x,
                                            const float* __restrict__ W,
                                            const float* __restrict__ cw, // null -> 1/1152
                                            float* __restrict__ s_part,
                                            unsigned short* __restrict__ xTh,
                                            unsigned short* __restrict__ xTl,
                                            const float* __restrict__ bcsrc,
                                            float* __restrict__ out,
                                            int tail)
{
    __shared__ ShMem sh;
    const int bid = blockIdx.x;
    const int tid = threadIdx.x;

    if (bid >= 768) {
        if (tail == 1) {
            // xT transpose+split: m-chunk of 16, all 256 b.
            const int m0 = (bid - 768) * 16;
            const int b = tid;
#pragma unroll
            for (int q = 0; q < 4; ++q) {
                const float4 v = reinterpret_cast<const float4*>(x)[(size_t)b * 2304 + (m0 >> 2) + q];
                const unsigned short h0 = f2bf(v.x), h1 = f2bf(v.y), h2 = f2bf(v.z), h3 = f2bf(v.w);
                sh.t.Th[q * 4 + 0][b] = (short)h0;
                sh.t.Th[q * 4 + 1][b] = (short)h1;
                sh.t.Th[q * 4 + 2][b] = (short)h2;
                sh.t.Th[q * 4 + 3][b] = (short)h3;
                sh.t.Tl[q * 4 + 0][b] = (short)f2bf(v.x - bf2f(h0));
                sh.t.Tl[q * 4 + 1][b] = (short)f2bf(v.y - bf2f(h1));
                sh.t.Tl[q * 4 + 2][b] = (short)f2bf(v.z - bf2f(h2));
                sh.t.Tl[q * 4 + 3][b] = (short)f2bf(v.w - bf2f(h3));
            }
            __syncthreads();
            const int m = tid >> 4, seg = tid & 15;
            const size_t o = (size_t)(m0 + m) * 256 + seg * 16;
            *reinterpret_cast<uint4*>(xTh + o) = *reinterpret_cast<const uint4*>(&sh.t.Th[m][seg * 16]);
            *reinterpret_cast<uint4*>(xTh + o + 8) = *reinterpret_cast<const uint4*>(&sh.t.Th[m][seg * 16 + 8]);
            *reinterpret_cast<uint4*>(xTl + o) = *reinterpret_cast<const uint4*>(&sh.t.Tl[m][seg * 16]);
            *reinterpret_cast<uint4*>(xTl + o + 8) = *reinterpret_cast<const uint4*>(&sh.t.Tl[m][seg * 16 + 8]);
        } else {
            // c_out broadcast: 2880 blocks x 256 float4 stores
            const int i = (bid - 768) * 256 + tid;
            const float4 v = reinterpret_cast<const float4*>(bcsrc)[i % 2880];
            reinterpret_cast<float4*>(out + 40960)[i] = v;
        }
        return;
    }

    const int xcd  = bid & 7;
    const int j    = bid >> 3;            // 0..95
    const int kb   = (j % 12) * 8 + xcd;  // 0..95
    const int mtnt = j / 12;              // 0..7
    const int mt = mtnt >> 1;
    const int nt = mtnt & 1;
    const int w    = tid >> 6;
    const int lane = tid & 63;
    const int l15  = lane & 15;
    const int lqw  = lane >> 4;
    const int row  = mt * 64 + w * 16 + l15;
    const int n0   = nt * 80;
    const int r_base = kb * 12;

    // A prefetch in f32 (2 float4 per ks = same bytes as bf16 h+l pair)
    float4 af[3][2];
    const float* xrow = x + (size_t)row * 9216 + kb * 96 + lqw * 8;
#pragma unroll
    for (int ks = 0; ks < 3; ++ks) {
        af[ks][0] = *reinterpret_cast<const float4*>(xrow + ks * 32);
        af[ks][1] = *reinterpret_cast<const float4*>(xrow + ks * 32 + 4);
    }

    // stage cij for the slab's 12 routes
    if (tid < 120) sh.g.cl[tid] = cw ? cw[r_base * 10 + tid] : (1.0f / 1152.0f);
    __syncthreads();

    // B staging with inline scale+split: chunk (n, ch); GLOBAL column gn = n0+n.
    for (int idx = tid; idx < 960; idx += 256) {
        const int n = idx / 12, ch = idx % 12;
        const int gn = n0 + n;
        const int c = gn >> 4, o = gn & 15;
        const float sc = sh.g.cl[ch * 10 + c];
        const float* wp = &W[(size_t)(r_base + ch) * 1280 + c * 128 + o * 8];
        const float4 w0 = *reinterpret_cast<const float4*>(wp);
        const float4 w1 = *reinterpret_cast<const float4*>(wp + 4);
        float v[8] = { w0.x * sc, w0.y * sc, w0.z * sc, w0.w * sc,
                       w1.x * sc, w1.y * sc, w1.z * sc, w1.w * sc };
        short8v hv, lv;
#pragma unroll
        for (int q = 0; q < 8; ++q) {
            const unsigned short h = f2bf(v[q]);
            hv[q] = (short)h;
            lv[q] = (short)f2bf(v[q] - bf2f(h));
        }
        *reinterpret_cast<short8v*>(&sh.g.Bs[0][ch][n][0]) = hv;
        *reinterpret_cast<short8v*>(&sh.g.Bs[1][ch][n][0]) = lv;
    }

    // A split to bf16 hi/lo in registers (identical f2bf arithmetic)
    short8v ah[3], al[3];
#pragma unroll
    for (int ks = 0; ks < 3; ++ks) {
        const float* av = reinterpret_cast<const float*>(&af[ks][0]);
#pragma unroll
        for (int q = 0; q < 8; ++q) {
            const unsigned short h = f2bf(av[q]);
            ah[ks][q] = (short)h;
            al[ks][q] = (short)f2bf(av[q] - bf2f(h));
        }
    }
    __syncthreads();

    f32x4 acc[5];
#pragma unroll
    for (int t = 0; t < 5; ++t) acc[t] = (f32x4){0.f, 0.f, 0.f, 0.f};

#pragma unroll
    for (int ks = 0; ks < 3; ++ks) {
        const int ch = ks * 4 + lqw;
#pragma unroll
        for (int t = 0; t < 5; ++t) {
            const short8v bh = *reinterpret_cast<const short8v*>(&sh.g.Bs[0][ch][t * 16 + l15][0]);
            const short8v bl = *reinterpret_cast<const short8v*>(&sh.g.Bs[1][ch][t * 16 + l15][0]);
            acc[t] = __builtin_amdgcn_mfma_f32_16x16x32_bf16(ah[ks], bh, acc[t], 0, 0, 0);
            acc[t] = __builtin_amdgcn_mfma_f32_16x16x32_bf16(ah[ks], bl, acc[t], 0, 0, 0);
            acc[t] = __builtin_amdgcn_mfma_f32_16x16x32_bf16(al[ks], bh, acc[t], 0, 0, 0);
        }
    }

    const int crow0 = mt * 64 + w * 16 + lqw * 4;
#pragma unroll
    for (int t = 0; t < 5; ++t) {
#pragma unroll
        for (int v = 0; v < 4; ++v) {
            s_part[((size_t)kb * 256 + crow0 + v) * 160 + n0 + t * 16 + l15] = acc[t][v];
        }
    }
}

// ---------------------------------------------------------------------------
// k_rvT: v[b][n] = squash(sum_kb s_part) -> write bf16 hi/lo TRANSPOSED vT[n][b].
// grid 256 (one b per block), block 192 (160 active = n).
__global__ __launch_bounds__(192) void k_rvT(const float* __restrict__ s_part,
                                             unsigned short* __restrict__ vTh,
                                             unsigned short* __restrict__ vTl)
{
    const int b = blockIdx.x;
    const int n = threadIdx.x;
    if (n < 160) {
        const float* p = s_part + (size_t)b * 160 + n;
        float s0 = 0.f, s1 = 0.f, s2 = 0.f, s3 = 0.f, s4 = 0.f, s5 = 0.f, s6 = 0.f, s7 = 0.f;
#pragma unroll
        for (int kbv = 0; kbv < 96; kbv += 8) {
            s0 += p[(size_t)(kbv + 0) * 40960];
            s1 += p[(size_t)(kbv + 1) * 40960];
            s2 += p[(size_t)(kbv + 2) * 40960];
            s3 += p[(size_t)(kbv + 3) * 40960];
            s4 += p[(size_t)(kbv + 4) * 40960];
            s5 += p[(size_t)(kbv + 5) * 40960];
            s6 += p[(size_t)(kbv + 6) * 40960];
            s7 += p[(size_t)(kbv + 7) * 40960];
        }
        const float s = ((s0 + s1) + (s2 + s3)) + ((s4 + s5) + (s6 + s7));
        float sq = s * s;
#pragma unroll
        for (int off = 1; off < 16; off <<= 1) sq += __shfl_xor(sq, off, 16);
        const float scale = (sq / (1.f + sq)) / sqrtf(sq + 1e-9f);
        const float val = s * scale;
        const unsigned short h = f2bf(val);
        vTh[n * 256 + b] = h;
        vTl[n * 256 + b] = f2bf(val - bf2f(h));
    }
}

// ---------------------------------------------------------------------------
// k_aM: agreement via MFMA. T^T = vT(160x256) x x(256x9216); then
// dbp[kh][r][c] = sum_{i,o} W[r][c][o][i] * T[m=r*8+i][n=c*16+o].
// grid 1152 = mt(576, 16 m = 2 routes) x kh(2, 128-batch halves); block 128.
__global__ __launch_bounds__(128) void k_aM(const unsigned short* __restrict__ vTh,
                                            const unsigned short* __restrict__ vTl,
                                            const unsigned short* __restrict__ xTh,
                                            const unsigned short* __restrict__ xTl,
                                            const float* __restrict__ W,
                                            float* __restrict__ dbp)
{
    __shared__ float dbl[20];
    const int mt = blockIdx.x >> 1;
    const int kh = blockIdx.x & 1;
    const int m0 = mt * 16;
    const int r0 = m0 >> 3;
    const int b0 = kh * 128;
    const int tid  = threadIdx.x;
    const int w    = tid >> 6;
    const int lane = tid & 63;
    const int l15  = lane & 15;
    const int lqw  = lane >> 4;
    if (tid < 20) dbl[tid] = 0.f;

    const size_t xbase = (size_t)(m0 + l15) * 256 + b0 + lqw * 8;

    f32x4 acc[5];
#pragma unroll
    for (int t = 0; t < 5; ++t) acc[t] = (f32x4){0.f, 0.f, 0.f, 0.f};

#pragma unroll
    for (int ks = 0; ks < 4; ++ks) {
        const short8v bh = *reinterpret_cast<const short8v*>(xTh + xbase + ks * 32);
        const short8v bl = *reinterpret_cast<const short8v*>(xTl + xbase + ks * 32);
#pragma unroll
        for (int t = 0; t < 5; ++t) {
            const size_t vbase = (size_t)(w * 80 + t * 16 + l15) * 256 + b0 + lqw * 8 + ks * 32;
            const short8v ah = *reinterpret_cast<const short8v*>(vTh + vbase);
            const short8v al = *reinterpret_cast<const short8v*>(vTl + vbase);
            acc[t] = __builtin_amdgcn_mfma_f32_16x16x32_bf16(ah, bh, acc[t], 0, 0, 0);
            acc[t] = __builtin_amdgcn_mfma_f32_16x16x32_bf16(ah, bl, acc[t], 0, 0, 0);
            acc[t] = __builtin_amdgcn_mfma_f32_16x16x32_bf16(al, bh, acc[t], 0, 0, 0);
        }
    }

    __syncthreads();   // dbl init visible
    const int rloc = l15 >> 3;
    const int i = l15 & 7;
    const int r = r0 + rloc;
#pragma unroll
    for (int t = 0; t < 5; ++t) {
        const int c = w * 5 + t;
        const float* wp = &W[(((size_t)(r * 10 + c) * 16 + lqw * 4) * 8) + i];
        float pv = wp[0] * acc[t][0] + wp[8] * acc[t][1] + wp[16] * acc[t][2] + wp[24] * acc[t][3];
        pv += __shfl_xor(pv, 16);
        pv += __shfl_xor(pv, 32);
        pv += __shfl_xor(pv, 1);
        pv += __shfl_xor(pv, 2);
        pv += __shfl_xor(pv, 4);
        if ((lane & 55) == 0)            // lanes 0 (r0) and 8 (r0+1)
            dbl[rloc * 10 + c] = pv;
    }
    __syncthreads();
    if (tid < 20) dbp[(size_t)kh * 11520 + (r0 + tid / 10) * 10 + (tid % 10)] = dbl[tid];
}

// ---------------------------------------------------------------------------
// k_sm: bnew = bprev + (sum of 2 dbp parts)/256 ; c = softmax over routes
__global__ __launch_bounds__(128) void k_sm(const float* __restrict__ bprev,
                                            const float* __restrict__ dbp,
                                            float* __restrict__ bnew,
                                            float* __restrict__ cij)
{
    __shared__ float red[2];
    __shared__ float red2[2];
    const int c = blockIdx.x;
    const int tid = threadIdx.x;
    float bv[9];
#pragma unroll
    for (int j = 0; j < 9; ++j) {
        const int idx = (tid + j * 128) * 10 + c;
        const float d = dbp[idx] + dbp[11520 + idx];
        bv[j] = (bprev ? bprev[idx] : 0.f) + d * (1.0f / 256.0f);
    }
    float mx = bv[0];
#pragma unroll
    for (int j = 1; j < 9; ++j) mx = fmaxf(mx, bv[j]);
#pragma unroll
    for (int off = 1; off < 64; off <<= 1) mx = fmaxf(mx, __shfl_xor(mx, off, 64));
    if ((tid & 63) == 0) red[tid >> 6] = mx;
    __syncthreads();
    mx = fmaxf(red[0], red[1]);
    float es[9], lsum = 0.f;
#pragma unroll
    for (int j = 0; j < 9; ++j) { es[j] = expf(bv[j] - mx); lsum += es[j]; }
#pragma unroll
    for (int off = 1; off < 64; off <<= 1) lsum += __shfl_xor(lsum, off, 64);
    if ((tid & 63) == 0) red2[tid >> 6] = lsum;
    __syncthreads();
    const float inv = 1.f / (red2[0] + red2[1]);
#pragma unroll
    for (int j = 0; j < 9; ++j) {
        const int idx = (tid + j * 128) * 10 + c;
        bnew[idx] = bv[j];
        cij[idx] = es[j] * inv;
    }
}

// ---------------------------------------------------------------------------
// k_rv: reduce+squash s_part -> out v (grid 160; c_out handled by k_sM tail).
__global__ __launch_bounds__(256) void k_rv(const float* __restrict__ s_part,
                                            float* __restrict__ out)
{
    const int e = blockIdx.x * 256 + threadIdx.x;
    float s0 = 0.f, s1 = 0.f, s2 = 0.f, s3 = 0.f;
#pragma unroll
    for (int kbv = 0; kbv < 96; kbv += 4) {
        s0 += s_part[(size_t)(kbv + 0) * 40960 + e];
        s1 += s_part[(size_t)(kbv + 1) * 40960 + e];
        s2 += s_part[(size_t)(kbv + 2) * 40960 + e];
        s3 += s_part[(size_t)(kbv + 3) * 40960 + e];
    }
    const float s = (s0 + s1) + (s2 + s3);
    float sq = s * s;
#pragma unroll
    for (int off = 1; off < 16; off <<= 1) sq += __shfl_xor(sq, off, 16);
    const float scale = (sq / (1.f + sq)) / sqrtf(sq + 1e-9f);
    out[e] = s * scale;
}

// ---------------------------------------------------------------------------
extern "C" void kernel_launch(void* const* d_in, const int* in_sizes, int n_in,
                              void* d_out, int out_size, void* d_ws, size_t ws_size,
                              hipStream_t stream)
{
    const float* x = (const float*)d_in[0];
    const float* W = (const float*)d_in[1];
    float* out = (float*)d_out;

    unsigned short* xTh = (unsigned short*)d_ws;      // 2359296 shorts each
    unsigned short* xTl = xTh + 2359296;
    unsigned short* vTh = xTl + 2359296;              // 40960 shorts each
    unsigned short* vTl = vTh + 40960;
    float* s_part = (float*)(vTl + 40960 + 32);       // 96*40960 f32 (aligned pad)
    float* b1   = s_part + 3932160;
    float* b2   = b1 + 11520;
    float* c2   = b2 + 11520;
    float* c3   = c2 + 11520;
    float* dbp0 = c3 + 11520;
    float* dbp1 = dbp0 + 23040;

    // ---- iteration 1 (c uniform = 1/1152 inline; tail = xT transpose) ----
    k_sM<<<768 + 576, 256, 0, stream>>>(x, W, nullptr, s_part,
                                        xTh, xTl, nullptr, out, 1);
    k_rvT<<<256, 192, 0, stream>>>(s_part, vTh, vTl);
    k_aM<<<1152, 128, 0, stream>>>(vTh, vTl, xTh, xTl, W, dbp0);
    k_sm<<<10, 128, 0, stream>>>(nullptr, dbp0, b1, c2);

    // ---- iteration 2 ----
    k_sM<<<768, 256, 0, stream>>>(x, W, c2, s_part,
                                  xTh, xTl, nullptr, out, 0);
    k_rvT<<<256, 192, 0, stream>>>(s_part, vTh, vTl);
    k_aM<<<1152, 128, 0, stream>>>(vTh, vTl, xTh, xTl, W, dbp1);
    k_sm<<<10, 128, 0, stream>>>(b1, dbp1, b2, c3);

    // ---- iteration 3 (tail = c_out broadcast) + v squash ----
    k_sM<<<768 + 2880, 256, 0, stream>>>(x, W, c3, s_part,
                                         xTh, xTl, c3, out, 2);
    k_rv<<<160, 256, 0, stream>>>(s_part, out);
}

// Round 19
// 104.415 us; speedup vs baseline: 5.5442x; 1.0044x over previous
//
#include <hip/hip_runtime.h>
#include <math.h>

// Capsule routing, fused. Both GEMMs via bf16 hi/lo-split MFMA (hh+hl+lh).
// x: [256][9216] f32   W: [1152][10][16][8] f32
// out: v [256][10][16] (40960) then c_out broadcast [256][1152][10] (2949120)
// 10 launches. KB=48 split-K (each GEMM block covers K=192 via a 2-chunk
// register-accumulated loop); grid recovered by nt=5 (BN=32) -> 960 blocks.
// s_part halves to 7.9 MB/iter; xT-transpose + c_out-broadcast ride as tails.

typedef __attribute__((ext_vector_type(8))) short short8v;
typedef __attribute__((ext_vector_type(4))) float f32x4;

__device__ __forceinline__ unsigned short f2bf(float f) {
    unsigned u = __float_as_uint(f);
    u += 0x7FFFu + ((u >> 16) & 1u);          // round-to-nearest-even
    return (unsigned short)(u >> 16);
}
__device__ __forceinline__ float bf2f(unsigned short h) {
    return __uint_as_float(((unsigned)h) << 16);
}

// ---------------------------------------------------------------------------
// Shared-memory union: GEMM staging vs transpose-tail staging.
union ShMem {
    struct { alignas(16) short Bs[2][12][32][8]; float cl[240]; } g;  // 13248 B
    struct { short Th[16][256]; short Tl[16][256]; } t;               // 16384 B
};

#define GEMM_BLOCKS 960

// ---------------------------------------------------------------------------
// k_sM: blocks 0..959: s_part[kb][b][n] = sum_{k in slab} x[b][k]*(cij*W)[k][n].
//   work = kb(48, K=192) x mt(4, BM=64) x nt(5, BN=32); block 256 = 4 waves.
//   K processed in 2 chunks of 96, acc carried in registers across chunks.
//   Swizzle: kb = (j%6)*8 + (bid&7) — all 20 workers of a kb on one XCD.
//   A loaded as f32 x and RNE-split in registers (identical numerics).
// blocks >= 960: tail==1 -> xT hi/lo transpose; tail==2 -> c_out broadcast.
__global__ __launch_bounds__(256) void k_sM(const float* __restrict__ x,
                                            const float* __restrict__ W,
                                            const float* __restrict__ cw, // null -> 1/1152
                                            float* __restrict__ s_part,
                                            unsigned short* __restrict__ xTh,
                                            unsigned short* __restrict__ xTl,
                                            const float* __restrict__ bcsrc,
                                            float* __restrict__ out,
                                            int tail)
{
    __shared__ ShMem sh;
    const int bid = blockIdx.x;
    const int tid = threadIdx.x;

    if (bid >= GEMM_BLOCKS) {
        if (tail == 1) {
            // xT transpose+split: m-chunk of 16, all 256 b.
            const int m0 = (bid - GEMM_BLOCKS) * 16;
            const int b = tid;
#pragma unroll
            for (int q = 0; q < 4; ++q) {
                const float4 v = reinterpret_cast<const float4*>(x)[(size_t)b * 2304 + (m0 >> 2) + q];
                const unsigned short h0 = f2bf(v.x), h1 = f2bf(v.y), h2 = f2bf(v.z), h3 = f2bf(v.w);
                sh.t.Th[q * 4 + 0][b] = (short)h0;
                sh.t.Th[q * 4 + 1][b] = (short)h1;
                sh.t.Th[q * 4 + 2][b] = (short)h2;
                sh.t.Th[q * 4 + 3][b] = (short)h3;
                sh.t.Tl[q * 4 + 0][b] = (short)f2bf(v.x - bf2f(h0));
                sh.t.Tl[q * 4 + 1][b] = (short)f2bf(v.y - bf2f(h1));
                sh.t.Tl[q * 4 + 2][b] = (short)f2bf(v.z - bf2f(h2));
                sh.t.Tl[q * 4 + 3][b] = (short)f2bf(v.w - bf2f(h3));
            }
            __syncthreads();
            const int m = tid >> 4, seg = tid & 15;
            const size_t o = (size_t)(m0 + m) * 256 + seg * 16;
            *reinterpret_cast<uint4*>(xTh + o) = *reinterpret_cast<const uint4*>(&sh.t.Th[m][seg * 16]);
            *reinterpret_cast<uint4*>(xTh + o + 8) = *reinterpret_cast<const uint4*>(&sh.t.Th[m][seg * 16 + 8]);
            *reinterpret_cast<uint4*>(xTl + o) = *reinterpret_cast<const uint4*>(&sh.t.Tl[m][seg * 16]);
            *reinterpret_cast<uint4*>(xTl + o + 8) = *reinterpret_cast<const uint4*>(&sh.t.Tl[m][seg * 16 + 8]);
        } else {
            // c_out broadcast: 2880 blocks x 256 float4 stores
            const int i = (bid - GEMM_BLOCKS) * 256 + tid;
            const float4 v = reinterpret_cast<const float4*>(bcsrc)[i % 2880];
            reinterpret_cast<float4*>(out + 40960)[i] = v;
        }
        return;
    }

    const int xcd  = bid & 7;
    const int j    = bid >> 3;            // 0..119
    const int kb   = (j % 6) * 8 + xcd;   // 0..47
    const int mtnt = j / 6;               // 0..19
    const int mt = mtnt / 5;              // 0..3
    const int nt = mtnt % 5;              // 0..4
    const int w    = tid >> 6;
    const int lane = tid & 63;
    const int l15  = lane & 15;
    const int lqw  = lane >> 4;
    const int row  = mt * 64 + w * 16 + l15;
    const int n0   = nt * 32;
    const int r_base = kb * 24;           // 24 routes per K=192 slab

    // A prefetch in f32: both chunks (2 x 3 ks x 8 floats = 48 f32)
    float4 af[2][3][2];
    const float* xrow = x + (size_t)row * 9216 + kb * 192 + lqw * 8;
#pragma unroll
    for (int c = 0; c < 2; ++c)
#pragma unroll
        for (int ks = 0; ks < 3; ++ks) {
            af[c][ks][0] = *reinterpret_cast<const float4*>(xrow + c * 96 + ks * 32);
            af[c][ks][1] = *reinterpret_cast<const float4*>(xrow + c * 96 + ks * 32 + 4);
        }

    // stage cij for the slab's 24 routes
    if (tid < 240) sh.g.cl[tid] = cw ? cw[r_base * 10 + tid] : (1.0f / 1152.0f);
    __syncthreads();

    f32x4 acc[2];
#pragma unroll
    for (int t = 0; t < 2; ++t) acc[t] = (f32x4){0.f, 0.f, 0.f, 0.f};

    for (int chunk = 0; chunk < 2; ++chunk) {
        // B staging with inline scale+split: 384 chunks (12 ch x 32 n)
        for (int idx = tid; idx < 384; idx += 256) {
            const int n = idx / 12, ch = idx % 12;
            const int gn = n0 + n;
            const int c = gn >> 4, o = gn & 15;
            const int rr = chunk * 12 + ch;          // route within slab
            const float sc = sh.g.cl[rr * 10 + c];
            const float* wp = &W[(size_t)(r_base + rr) * 1280 + c * 128 + o * 8];
            const float4 w0 = *reinterpret_cast<const float4*>(wp);
            const float4 w1 = *reinterpret_cast<const float4*>(wp + 4);
            float v[8] = { w0.x * sc, w0.y * sc, w0.z * sc, w0.w * sc,
                           w1.x * sc, w1.y * sc, w1.z * sc, w1.w * sc };
            short8v hv, lv;
#pragma unroll
            for (int q = 0; q < 8; ++q) {
                const unsigned short h = f2bf(v[q]);
                hv[q] = (short)h;
                lv[q] = (short)f2bf(v[q] - bf2f(h));
            }
            *reinterpret_cast<short8v*>(&sh.g.Bs[0][ch][n][0]) = hv;
            *reinterpret_cast<short8v*>(&sh.g.Bs[1][ch][n][0]) = lv;
        }

        // A split to bf16 hi/lo in registers for this chunk
        short8v ah[3], al[3];
#pragma unroll
        for (int ks = 0; ks < 3; ++ks) {
            const float* av = reinterpret_cast<const float*>(&af[chunk][ks][0]);
#pragma unroll
            for (int q = 0; q < 8; ++q) {
                const unsigned short h = f2bf(av[q]);
                ah[ks][q] = (short)h;
                al[ks][q] = (short)f2bf(av[q] - bf2f(h));
            }
        }
        __syncthreads();

#pragma unroll
        for (int ks = 0; ks < 3; ++ks) {
            const int ch = ks * 4 + lqw;
#pragma unroll
            for (int t = 0; t < 2; ++t) {
                const short8v bh = *reinterpret_cast<const short8v*>(&sh.g.Bs[0][ch][t * 16 + l15][0]);
                const short8v bl = *reinterpret_cast<const short8v*>(&sh.g.Bs[1][ch][t * 16 + l15][0]);
                acc[t] = __builtin_amdgcn_mfma_f32_16x16x32_bf16(ah[ks], bh, acc[t], 0, 0, 0);
                acc[t] = __builtin_amdgcn_mfma_f32_16x16x32_bf16(ah[ks], bl, acc[t], 0, 0, 0);
                acc[t] = __builtin_amdgcn_mfma_f32_16x16x32_bf16(al[ks], bh, acc[t], 0, 0, 0);
            }
        }
        if (chunk == 0) __syncthreads();   // protect Bs before restaging
    }

    const int crow0 = mt * 64 + w * 16 + lqw * 4;
#pragma unroll
    for (int t = 0; t < 2; ++t) {
#pragma unroll
        for (int v = 0; v < 4; ++v) {
            s_part[((size_t)kb * 256 + crow0 + v) * 160 + n0 + t * 16 + l15] = acc[t][v];
        }
    }
}

// ---------------------------------------------------------------------------
// k_rvT: v[b][n] = squash(sum_kb s_part) -> write bf16 hi/lo TRANSPOSED vT[n][b].
// grid 256 (one b per block), block 192 (160 active = n). Depth 48.
__global__ __launch_bounds__(192) void k_rvT(const float* __restrict__ s_part,
                                             unsigned short* __restrict__ vTh,
                                             unsigned short* __restrict__ vTl)
{
    const int b = blockIdx.x;
    const int n = threadIdx.x;
    if (n < 160) {
        const float* p = s_part + (size_t)b * 160 + n;
        float s0 = 0.f, s1 = 0.f, s2 = 0.f, s3 = 0.f, s4 = 0.f, s5 = 0.f, s6 = 0.f, s7 = 0.f;
#pragma unroll
        for (int kbv = 0; kbv < 48; kbv += 8) {
            s0 += p[(size_t)(kbv + 0) * 40960];
            s1 += p[(size_t)(kbv + 1) * 40960];
            s2 += p[(size_t)(kbv + 2) * 40960];
            s3 += p[(size_t)(kbv + 3) * 40960];
            s4 += p[(size_t)(kbv + 4) * 40960];
            s5 += p[(size_t)(kbv + 5) * 40960];
            s6 += p[(size_t)(kbv + 6) * 40960];
            s7 += p[(size_t)(kbv + 7) * 40960];
        }
        const float s = ((s0 + s1) + (s2 + s3)) + ((s4 + s5) + (s6 + s7));
        float sq = s * s;
#pragma unroll
        for (int off = 1; off < 16; off <<= 1) sq += __shfl_xor(sq, off, 16);
        const float scale = (sq / (1.f + sq)) / sqrtf(sq + 1e-9f);
        const float val = s * scale;
        const unsigned short h = f2bf(val);
        vTh[n * 256 + b] = h;
        vTl[n * 256 + b] = f2bf(val - bf2f(h));
    }
}

// ---------------------------------------------------------------------------
// k_aM: agreement via MFMA. T^T = vT(160x256) x x(256x9216); then
// dbp[kh][r][c] = sum_{i,o} W[r][c][o][i] * T[m=r*8+i][n=c*16+o].
// grid 1152 = mt(576, 16 m = 2 routes) x kh(2, 128-batch halves); block 128.
__global__ __launch_bounds__(128) void k_aM(const unsigned short* __restrict__ vTh,
                                            const unsigned short* __restrict__ vTl,
                                            const unsigned short* __restrict__ xTh,
                                            const unsigned short* __restrict__ xTl,
                                            const float* __restrict__ W,
                                            float* __restrict__ dbp)
{
    __shared__ float dbl[20];
    const int mt = blockIdx.x >> 1;
    const int kh = blockIdx.x & 1;
    const int m0 = mt * 16;
    const int r0 = m0 >> 3;
    const int b0 = kh * 128;
    const int tid  = threadIdx.x;
    const int w    = tid >> 6;
    const int lane = tid & 63;
    const int l15  = lane & 15;
    const int lqw  = lane >> 4;
    if (tid < 20) dbl[tid] = 0.f;

    const size_t xbase = (size_t)(m0 + l15) * 256 + b0 + lqw * 8;

    f32x4 acc[5];
#pragma unroll
    for (int t = 0; t < 5; ++t) acc[t] = (f32x4){0.f, 0.f, 0.f, 0.f};

#pragma unroll
    for (int ks = 0; ks < 4; ++ks) {
        const short8v bh = *reinterpret_cast<const short8v*>(xTh + xbase + ks * 32);
        const short8v bl = *reinterpret_cast<const short8v*>(xTl + xbase + ks * 32);
#pragma unroll
        for (int t = 0; t < 5; ++t) {
            const size_t vbase = (size_t)(w * 80 + t * 16 + l15) * 256 + b0 + lqw * 8 + ks * 32;
            const short8v ah = *reinterpret_cast<const short8v*>(vTh + vbase);
            const short8v al = *reinterpret_cast<const short8v*>(vTl + vbase);
            acc[t] = __builtin_amdgcn_mfma_f32_16x16x32_bf16(ah, bh, acc[t], 0, 0, 0);
            acc[t] = __builtin_amdgcn_mfma_f32_16x16x32_bf16(ah, bl, acc[t], 0, 0, 0);
            acc[t] = __builtin_amdgcn_mfma_f32_16x16x32_bf16(al, bh, acc[t], 0, 0, 0);
        }
    }

    __syncthreads();   // dbl init visible
    const int rloc = l15 >> 3;
    const int i = l15 & 7;
    const int r = r0 + rloc;
#pragma unroll
    for (int t = 0; t < 5; ++t) {
        const int c = w * 5 + t;
        const float* wp = &W[(((size_t)(r * 10 + c) * 16 + lqw * 4) * 8) + i];
        float pv = wp[0] * acc[t][0] + wp[8] * acc[t][1] + wp[16] * acc[t][2] + wp[24] * acc[t][3];
        pv += __shfl_xor(pv, 16);
        pv += __shfl_xor(pv, 32);
        pv += __shfl_xor(pv, 1);
        pv += __shfl_xor(pv, 2);
        pv += __shfl_xor(pv, 4);
        if ((lane & 55) == 0)            // lanes 0 (r0) and 8 (r0+1)
            dbl[rloc * 10 + c] = pv;
    }
    __syncthreads();
    if (tid < 20) dbp[(size_t)kh * 11520 + (r0 + tid / 10) * 10 + (tid % 10)] = dbl[tid];
}

// ---------------------------------------------------------------------------
// k_sm: bnew = bprev + (sum of 2 dbp parts)/256 ; c = softmax over routes
__global__ __launch_bounds__(128) void k_sm(const float* __restrict__ bprev,
                                            const float* __restrict__ dbp,
                                            float* __restrict__ bnew,
                                            float* __restrict__ cij)
{
    __shared__ float red[2];
    __shared__ float red2[2];
    const int c = blockIdx.x;
    const int tid = threadIdx.x;
    float bv[9];
#pragma unroll
    for (int j = 0; j < 9; ++j) {
        const int idx = (tid + j * 128) * 10 + c;
        const float d = dbp[idx] + dbp[11520 + idx];
        bv[j] = (bprev ? bprev[idx] : 0.f) + d * (1.0f / 256.0f);
    }
    float mx = bv[0];
#pragma unroll
    for (int j = 1; j < 9; ++j) mx = fmaxf(mx, bv[j]);
#pragma unroll
    for (int off = 1; off < 64; off <<= 1) mx = fmaxf(mx, __shfl_xor(mx, off, 64));
    if ((tid & 63) == 0) red[tid >> 6] = mx;
    __syncthreads();
    mx = fmaxf(red[0], red[1]);
    float es[9], lsum = 0.f;
#pragma unroll
    for (int j = 0; j < 9; ++j) { es[j] = expf(bv[j] - mx); lsum += es[j]; }
#pragma unroll
    for (int off = 1; off < 64; off <<= 1) lsum += __shfl_xor(lsum, off, 64);
    if ((tid & 63) == 0) red2[tid >> 6] = lsum;
    __syncthreads();
    const float inv = 1.f / (red2[0] + red2[1]);
#pragma unroll
    for (int j = 0; j < 9; ++j) {
        const int idx = (tid + j * 128) * 10 + c;
        bnew[idx] = bv[j];
        cij[idx] = es[j] * inv;
    }
}

// ---------------------------------------------------------------------------
// k_rv: reduce+squash s_part -> out v (grid 160). Depth 48.
__global__ __launch_bounds__(256) void k_rv(const float* __restrict__ s_part,
                                            float* __restrict__ out)
{
    const int e = blockIdx.x * 256 + threadIdx.x;
    float s0 = 0.f, s1 = 0.f, s2 = 0.f, s3 = 0.f;
#pragma unroll
    for (int kbv = 0; kbv < 48; kbv += 4) {
        s0 += s_part[(size_t)(kbv + 0) * 40960 + e];
        s1 += s_part[(size_t)(kbv + 1) * 40960 + e];
        s2 += s_part[(size_t)(kbv + 2) * 40960 + e];
        s3 += s_part[(size_t)(kbv + 3) * 40960 + e];
    }
    const float s = (s0 + s1) + (s2 + s3);
    float sq = s * s;
#pragma unroll
    for (int off = 1; off < 16; off <<= 1) sq += __shfl_xor(sq, off, 16);
    const float scale = (sq / (1.f + sq)) / sqrtf(sq + 1e-9f);
    out[e] = s * scale;
}

// ---------------------------------------------------------------------------
extern "C" void kernel_launch(void* const* d_in, const int* in_sizes, int n_in,
                              void* d_out, int out_size, void* d_ws, size_t ws_size,
                              hipStream_t stream)
{
    const float* x = (const float*)d_in[0];
    const float* W = (const float*)d_in[1];
    float* out = (float*)d_out;

    unsigned short* xTh = (unsigned short*)d_ws;      // 2359296 shorts each
    unsigned short* xTl = xTh + 2359296;
    unsigned short* vTh = xTl + 2359296;              // 40960 shorts each
    unsigned short* vTl = vTh + 40960;
    float* s_part = (float*)(vTl + 40960 + 32);       // 48*40960 f32 (aligned pad)
    float* b1   = s_part + 48 * 40960;
    float* b2   = b1 + 11520;
    float* c2   = b2 + 11520;
    float* c3   = c2 + 11520;
    float* dbp0 = c3 + 11520;
    float* dbp1 = dbp0 + 23040;

    // ---- iteration 1 (c uniform = 1/1152 inline; tail = xT transpose) ----
    k_sM<<<GEMM_BLOCKS + 576, 256, 0, stream>>>(x, W, nullptr, s_part,
                                                xTh, xTl, nullptr, out, 1);
    k_rvT<<<256, 192, 0, stream>>>(s_part, vTh, vTl);
    k_aM<<<1152, 128, 0, stream>>>(vTh, vTl, xTh, xTl, W, dbp0);
    k_sm<<<10, 128, 0, stream>>>(nullptr, dbp0, b1, c2);

    // ---- iteration 2 ----
    k_sM<<<GEMM_BLOCKS, 256, 0, stream>>>(x, W, c2, s_part,
                                          xTh, xTl, nullptr, out, 0);
    k_rvT<<<256, 192, 0, stream>>>(s_part, vTh, vTl);
    k_aM<<<1152, 128, 0, stream>>>(vTh, vTl, xTh, xTl, W, dbp1);
    k_sm<<<10, 128, 0, stream>>>(b1, dbp1, b2, c3);

    // ---- iteration 3 (tail = c_out broadcast) + v squash ----
    k_sM<<<GEMM_BLOCKS + 2880, 256, 0, stream>>>(x, W, c3, s_part,
                                                 xTh, xTl, c3, out, 2);
    k_rv<<<160, 256, 0, stream>>>(s_part, out);
}